// Round 1
// baseline (435.557 us; speedup 1.0000x reference)
//
#include <hip/hip_runtime.h>
#include <hip/hip_bf16.h>

#define GAMMA 0.25f

// Shapes: B=1024, C=3, H=64, D=256, NP=64 (8x8 grid of 8x8 patches),
//         M=1024, NH=8, R=32, P=8.  fp32 in/out.  out[b] = quad - coupling.

typedef __attribute__((ext_vector_type(8))) short short8;  // 8 bf16 (4 VGPRs)
typedef __attribute__((ext_vector_type(4))) float f32x4;   // 4 fp32 acc

__device__ __forceinline__ float dot4(float4 a, float4 b) {
  return fmaf(a.x, b.x, fmaf(a.y, b.y, fmaf(a.z, b.z, a.w * b.w)));
}

__device__ __forceinline__ void fma4(float4& a, float s, float4 w) {
  a.x = fmaf(s, w.x, a.x); a.y = fmaf(s, w.y, a.y);
  a.z = fmaf(s, w.z, a.z); a.w = fmaf(s, w.w, a.w);
}

__device__ __forceinline__ ushort f2bf(float f) {
  __hip_bfloat16 h = __float2bfloat16(f);  // RNE
  return *reinterpret_cast<ushort*>(&h);
}

__device__ __forceinline__ float bf2f(ushort u) {
  union { unsigned int i; float f; } v;
  v.i = ((unsigned int)u) << 16;
  return v.f;
}

// 256-thread block sum; result valid on all threads.
__device__ __forceinline__ float block_sum_256(float v, float* tmp) {
#pragma unroll
  for (int off = 32; off; off >>= 1) v += __shfl_down(v, off, 64);
  int w = threadIdx.x >> 6;
  if ((threadIdx.x & 63) == 0) tmp[w] = v;
  __syncthreads();
  return tmp[0] + tmp[1] + tmp[2] + tmp[3];
}

// ---------------------------------------------------------------------------
// Kernel 1: z-only pass. quad_z - phi_bias - phi_pos, and z -> bf16 (zb16).
// (x terms moved into k_enc_fused; x16 intermediate eliminated entirely.)
// ---------------------------------------------------------------------------
__global__ __launch_bounds__(256) void k_z_cvt(const float* __restrict__ z,
                                               const float* __restrict__ eb,
                                               const float* __restrict__ pb,
                                               float* __restrict__ out,
                                               ushort* __restrict__ zb16) {
  __shared__ float tmp[4];
  int b = blockIdx.x, t = threadIdx.x;
  const float4* zb = (const float4*)(z + (size_t)b * 16384);
  const float4* pb4 = (const float4*)pb;
  const float4* eb4 = (const float4*)eb;
  ushort4* z16o = (ushort4*)(zb16 + (size_t)b * 16384);
  float s = 0.f;
  for (int i = t; i < 4096; i += 256) {
    float4 zv = zb[i];
    float4 pv = pb4[i];
    float4 ev = eb4[i & 63];
    float4 c;
    c.x = pv.x + ev.x; c.y = pv.y + ev.y; c.z = pv.z + ev.z; c.w = pv.w + ev.w;
    s += 0.5f * dot4(zv, zv) - dot4(zv, c);
    ushort4 o;
    o.x = f2bf(zv.x); o.y = f2bf(zv.y); o.z = f2bf(zv.z); o.w = f2bf(zv.w);
    z16o[i] = o;
  }
  float r = block_sum_256(s, tmp);
  if (t == 0) out[b] = r;  // plain store: establishes out[b] for later atomics
}

// ---------------------------------------------------------------------------
// All small weight conversions in ONE launch (block ranges):
// [0,64) wq plain, [64,128) wk plain, [128,176) ew plain, [176,304) mw-transp.
// ---------------------------------------------------------------------------
__global__ __launch_bounds__(256) void k_cvt_weights(
    const float4* __restrict__ wq4, const float4* __restrict__ wk4,
    const float4* __restrict__ ew4, const float* __restrict__ mw,
    ushort4* __restrict__ wq16, ushort4* __restrict__ wk16,
    ushort4* __restrict__ ew16, ushort* __restrict__ mt) {
  int bid = blockIdx.x, t = threadIdx.x;
  if (bid < 176) {
    const float4* src; ushort4* dst; int i;
    if (bid < 64)       { src = wq4; dst = wq16; i = bid * 256 + t; }
    else if (bid < 128) { src = wk4; dst = wk16; i = (bid - 64) * 256 + t; }
    else                { src = ew4; dst = ew16; i = (bid - 128) * 256 + t; }
    float4 v = src[i];
    ushort4 o;
    o.x = f2bf(v.x); o.y = f2bf(v.y); o.z = f2bf(v.z); o.w = f2bf(v.w);
    dst[i] = o;
  } else {
    int j = (bid - 176) * 256 + t;  // 32768 threads
    int m = j >> 5, k8 = j & 31;
    ushort tmp[8];
#pragma unroll
    for (int i = 0; i < 8; ++i)
      tmp[i] = f2bf(mw[(size_t)(k8 * 8 + i) * 1024 + m]);
    ushort4 a, c;
    a.x = tmp[0]; a.y = tmp[1]; a.z = tmp[2]; a.w = tmp[3];
    c.x = tmp[4]; c.y = tmp[5]; c.z = tmp[6]; c.w = tmp[7];
    *(ushort4*)(mt + (size_t)m * 256 + k8 * 8) = a;
    *(ushort4*)(mt + (size_t)m * 256 + k8 * 8 + 4) = c;
  }
}

// ---------------------------------------------------------------------------
// Kernel 2 (fused): quad_x - phi_vis - phi_enc.
// Reads x fp32 ONCE (no x16 round-trip): stage x -> bf16 in 24 KB LDS while
// accumulating 0.5|x|^2 - vb.x; A-frags read from LDS (same indexing as the
// verified x16 path); B-frags (ew16, 96 KB) read DIRECTLY from global — the
// lane pattern is w-independent so all 4 waves hit L1 (per-ks working set
// 4 KB).  Epilogue dots acc against zb16 (L2-hot from k_z_cvt).
// ---------------------------------------------------------------------------
__global__ __launch_bounds__(256) void k_enc_fused(
    const float* __restrict__ x, const float* __restrict__ vb,
    const ushort* __restrict__ ew16, const ushort* __restrict__ zb16,
    float* __restrict__ out) {
  __shared__ ushort xs[12288];  // 24 KB: x[b] bf16, original NCHW layout
  __shared__ float tmp[4];
  const int b = blockIdx.x, t = threadIdx.x, l = t & 63, w = t >> 6;
  const int q = l >> 4, m = l & 15;

  const float4* xb = (const float4*)(x + (size_t)b * 12288);
  const float4* vb4 = (const float4*)vb;
  ushort4* xs4 = (ushort4*)xs;
  float s = 0.f;
  for (int i = t; i < 3072; i += 256) {
    float4 xv = xb[i];
    float4 bv = vb4[i];
    s += 0.5f * dot4(xv, xv) - dot4(bv, xv);
    ushort4 o;
    o.x = f2bf(xv.x); o.y = f2bf(xv.y); o.z = f2bf(xv.z); o.w = f2bf(xv.w);
    xs4[i] = o;
  }
  __syncthreads();

  const int p = 16 * w + m, gi = p >> 3, gj = p & 7;
  short8 a[6];
#pragma unroll
  for (int ks = 0; ks < 6; ++ks) {
    int k0 = ks * 32 + q * 8;
    int c = k0 >> 6, ii = (k0 & 63) >> 3;
    a[ks] = *(const short8*)(xs + c * 4096 + (gi * 8 + ii) * 64 + gj * 8);
  }

  f32x4 acc[16];
#pragma unroll
  for (int ct = 0; ct < 16; ++ct) acc[ct] = f32x4{0.f, 0.f, 0.f, 0.f};

#pragma unroll
  for (int ks = 0; ks < 6; ++ks) {
    const ushort* Bp = ew16 + (size_t)m * 192 + ks * 32 + q * 8;
#pragma unroll
    for (int ct = 0; ct < 16; ++ct) {
      short8 bv = *(const short8*)(Bp + (size_t)(16 * ct) * 192);
      acc[ct] = __builtin_amdgcn_mfma_f32_16x16x32_bf16(a[ks], bv, acc[ct], 0, 0, 0);
    }
  }

  const ushort* zrow = zb16 + (size_t)b * 16384;
#pragma unroll
  for (int ct = 0; ct < 16; ++ct) {
#pragma unroll
    for (int reg = 0; reg < 4; ++reg) {
      int pp = 16 * w + 4 * q + reg;
      s -= acc[ct][reg] * bf2f(zrow[pp * 256 + 16 * ct + m]);
    }
  }
  float r = block_sum_256(s, tmp);
  if (t == 0) atomicAdd(out + b, r);  // += quad_x - phi_vis - phi_enc
}

// ---------------------------------------------------------------------------
// Kernel 3 (MFMA v3): phi_mem.  One block per b (grid 1024).
// R9 theory: v2 was LDS-read-bound (17 ds_read_b128 per 16 MFMA per wave —
// every wave re-read the SAME 16 B-frags) and re-read zb16 4x.  v3: 4x4
// register blocking (4 A + 4 B reads per 16 MFMA); with the col-split each B
// fragment is consumed by exactly ONE wave once, so B staging has zero reuse
// -> read B straight from L2 (mt = 512 KB, L2-resident), no LDS B buffer, no
// main-loop barriers (compiler pipelines the global loads).  ct looped inside
// so zb16 is read once per b.
// ---------------------------------------------------------------------------
__global__ __launch_bounds__(256) void k_mem_v3(const ushort* __restrict__ zb,
                                                const ushort* __restrict__ mt,
                                                float* __restrict__ out) {
  __shared__ ushort zf[2048 * 8];  // 32 KB: z[b] fragment-ordered [w2][ks][l]
  __shared__ float tmp[4];
  const int t = threadIdx.x, l = t & 63, w = t >> 6;
  const int q = l >> 4, m = l & 15;
  const int b = blockIdx.x;

#pragma unroll
  for (int j = 0; j < 8; ++j) {
    int i = t + j * 256;
    int l2 = i & 63, ks = (i >> 6) & 7, w2 = i >> 9;
    short8 v = *(const short8*)(zb + ((size_t)b * 64 + 16 * w2 + (l2 & 15)) * 256
                                + ks * 32 + (l2 >> 4) * 8);
    *(short8*)(zf + (size_t)i * 8) = v;
  }
  __syncthreads();

  float s = 0.f;
  for (int ct = 0; ct < 4; ++ct) {
    f32x4 acc[4][4];
#pragma unroll
    for (int r = 0; r < 4; ++r)
#pragma unroll
      for (int c = 0; c < 4; ++c) acc[r][c] = f32x4{0.f, 0.f, 0.f, 0.f};

    // wave w owns mt rows [ct*256 + w*64, +64): col-tiles c -> rows +c*16
    const ushort* Bbase = mt + ((size_t)(ct * 256 + w * 64 + m)) * 256 + q * 8;
#pragma unroll
    for (int kc = 0; kc < 8; ++kc) {
      short8 a4[4], b4[4];
#pragma unroll
      for (int r = 0; r < 4; ++r)
        a4[r] = *(const short8*)(zf + (size_t)((r * 8 + kc) * 64 + l) * 8);
#pragma unroll
      for (int c = 0; c < 4; ++c)
        b4[c] = *(const short8*)(Bbase + (size_t)(c * 16) * 256 + kc * 32);
#pragma unroll
      for (int r = 0; r < 4; ++r)
#pragma unroll
        for (int c = 0; c < 4; ++c)
          acc[r][c] = __builtin_amdgcn_mfma_f32_16x16x32_bf16(a4[r], b4[c],
                                                              acc[r][c], 0, 0, 0);
    }
#pragma unroll
    for (int r = 0; r < 4; ++r)
#pragma unroll
      for (int c = 0; c < 4; ++c)
#pragma unroll
        for (int e = 0; e < 4; ++e) {
          float rr = fmaxf(acc[r][c][e], 0.f);
          s = fmaf(rr, rr, s);
        }
  }
  float r = block_sum_256(s, tmp);
  if (t == 0) atomicAdd(out + b, -r);
}

// ---------------------------------------------------------------------------
// Kernel 4 (MFMA v3): phi_att.  One block per b (grid 1024), loop all 8
// heads: per-block z A-frags loaded ONCE (was twice with the half split).
// Same verified per-head structure: proj MFMA with W from global (L2-hot),
// D->bf16->LDS (stride-40: 2-way bank aliasing only, free per m136),
// barrier, A=QK^T (one K=32 MFMA per n-tile), exp/shfl/log, barrier.
// __launch_bounds__(256,4) caps VGPR at 128 -> 4 blocks/CU residency keeps
// the W-load latency hidden by block-level overlap.
// ---------------------------------------------------------------------------
__global__ __launch_bounds__(256, 4) void k_attn_v3(
    const ushort* __restrict__ zb, const ushort* __restrict__ wq16,
    const ushort* __restrict__ wk16, float* __restrict__ out) {
  __shared__ ushort Qb[64 * 40];  // one head: [p][r], stride 40 halfwords
  __shared__ ushort Kb[64 * 40];
  __shared__ float tmp[4];
  const int t = threadIdx.x, l = t & 63, w = t >> 6;
  const int b = blockIdx.x;
  const int q = l >> 4, m = l & 15;

  // A-fragments of z[b] for m-tile w: reused across all 8 heads and Q/K.
  const ushort* Az = zb + ((size_t)b * 64 + 16 * w + m) * 256 + q * 8;
  short8 a[8];
#pragma unroll
  for (int ks = 0; ks < 8; ++ks) a[ks] = *(const short8*)(Az + ks * 32);

  float part = 0.f;
  for (int h = 0; h < 8; ++h) {
    f32x4 accq0 = f32x4{0.f, 0.f, 0.f, 0.f}, accq1 = accq0;
    f32x4 acck0 = accq0, acck1 = accq0;
    const ushort* Bq = wq16 + (size_t)h * 8192 + (size_t)m * 256 + q * 8;
    const ushort* Bk = wk16 + (size_t)h * 8192 + (size_t)m * 256 + q * 8;
#pragma unroll
    for (int ks = 0; ks < 8; ++ks) {
      short8 bq0 = *(const short8*)(Bq + ks * 32);
      short8 bq1 = *(const short8*)(Bq + 4096 + ks * 32);
      short8 bk0 = *(const short8*)(Bk + ks * 32);
      short8 bk1 = *(const short8*)(Bk + 4096 + ks * 32);
      accq0 = __builtin_amdgcn_mfma_f32_16x16x32_bf16(a[ks], bq0, accq0, 0, 0, 0);
      accq1 = __builtin_amdgcn_mfma_f32_16x16x32_bf16(a[ks], bq1, accq1, 0, 0, 0);
      acck0 = __builtin_amdgcn_mfma_f32_16x16x32_bf16(a[ks], bk0, acck0, 0, 0, 0);
      acck1 = __builtin_amdgcn_mfma_f32_16x16x32_bf16(a[ks], bk1, acck1, 0, 0, 0);
    }
    // D (row = 16w+4q+reg, col = r) -> bf16 -> LDS.
    const int rowbase = (16 * w + 4 * q) * 40;
#pragma unroll
    for (int reg = 0; reg < 4; ++reg) {
      Qb[rowbase + reg * 40 + m]      = f2bf(accq0[reg]);
      Qb[rowbase + reg * 40 + 16 + m] = f2bf(accq1[reg]);
      Kb[rowbase + reg * 40 + m]      = f2bf(acck0[reg]);
      Kb[rowbase + reg * 40 + 16 + m] = f2bf(acck1[reg]);
    }
    __syncthreads();

    // Phase 2: A-frag rows 16w+m, k=r=q*8..+7; B-frags from Kb per n-tile.
    short8 qa = *(const short8*)&Qb[(16 * w + m) * 40 + q * 8];
    f32x4 acc[4];
#pragma unroll
    for (int nt = 0; nt < 4; ++nt) {
      short8 kb = *(const short8*)&Kb[(16 * nt + m) * 40 + q * 8];
      acc[nt] = __builtin_amdgcn_mfma_f32_16x16x32_bf16(
          qa, kb, f32x4{0.f, 0.f, 0.f, 0.f}, 0, 0, 0);
    }
#pragma unroll
    for (int reg = 0; reg < 4; ++reg) {
      float e = __expf(GAMMA * acc[0][reg]) + __expf(GAMMA * acc[1][reg]) +
                __expf(GAMMA * acc[2][reg]) + __expf(GAMMA * acc[3][reg]);
      e += __shfl_xor(e, 1, 64);
      e += __shfl_xor(e, 2, 64);
      e += __shfl_xor(e, 4, 64);
      e += __shfl_xor(e, 8, 64);
      part += (m == 0) ? __logf(e) : 0.f;  // one log per row 16w+4q+reg
    }
    __syncthreads();  // all Qb/Kb reads done before next head's writes
  }
  float tot = block_sum_256(part, tmp);
  if (t == 0) atomicAdd(out + b, -tot * (1.0f / GAMMA));
}

// ---------------------------------------------------------------------------
// Fallback kernels (no-workspace tier).
// ---------------------------------------------------------------------------
__global__ __launch_bounds__(256) void k_xz(const float* __restrict__ x,
                                            const float* __restrict__ z,
                                            const float* __restrict__ vb,
                                            const float* __restrict__ eb,
                                            const float* __restrict__ pb,
                                            float* __restrict__ out) {
  __shared__ float tmp[4];
  int b = blockIdx.x, t = threadIdx.x;
  const float4* xb = (const float4*)(x + (size_t)b * 12288);
  const float4* vb4 = (const float4*)vb;
  float s = 0.f;
  for (int i = t; i < 3072; i += 256) {
    float4 xv = xb[i];
    float4 bv = vb4[i];
    s += 0.5f * dot4(xv, xv) - dot4(bv, xv);
  }
  const float4* zb = (const float4*)(z + (size_t)b * 16384);
  const float4* pb4 = (const float4*)pb;
  const float4* eb4 = (const float4*)eb;
  for (int i = t; i < 4096; i += 256) {
    float4 zv = zb[i];
    float4 pv = pb4[i];
    float4 ev = eb4[i & 63];
    float4 c;
    c.x = pv.x + ev.x; c.y = pv.y + ev.y; c.z = pv.z + ev.z; c.w = pv.w + ev.w;
    s += 0.5f * dot4(zv, zv) - dot4(zv, c);
  }
  float r = block_sum_256(s, tmp);
  if (t == 0) out[b] = r;
}

__global__ __launch_bounds__(256) void k_enc(const float* __restrict__ x,
                                             const float* __restrict__ z,
                                             const float* __restrict__ ew,
                                             float* __restrict__ out) {
  __shared__ float xs[12288];
  __shared__ float tmp[4];
  int b = blockIdx.x, t = threadIdx.x;
  const float4* xb4 = (const float4*)(x + (size_t)b * 12288);
  for (int i = t; i < 3072; i += 256) ((float4*)xs)[i] = xb4[i];
  __syncthreads();

  float acc[64];
#pragma unroll
  for (int p = 0; p < 64; ++p) acc[p] = 0.f;

  for (int k4 = 0; k4 < 48; ++k4) {
    float4 wv = *(const float4*)(ew + (size_t)t * 192 + k4 * 4);
    int c = k4 >> 4;
    int ii = (k4 >> 1) & 7;
    int jh = (k4 & 1) * 4;
    const float* base = xs + c * 4096 + ii * 64 + jh;
#pragma unroll
    for (int p = 0; p < 64; ++p) {
      float4 pv = *(const float4*)(base + (p >> 3) * 512 + (p & 7) * 8);
      acc[p] = fmaf(wv.x, pv.x,
               fmaf(wv.y, pv.y, fmaf(wv.z, pv.z, fmaf(wv.w, pv.w, acc[p]))));
    }
  }
  const float* zb = z + (size_t)b * 16384;
  float s = 0.f;
#pragma unroll
  for (int p = 0; p < 64; ++p) s += acc[p] * zb[p * 256 + t];
  float r = block_sum_256(s, tmp);
  if (t == 0) atomicAdd(out + b, -r);
}

__global__ __launch_bounds__(256) void k_mem(const float* __restrict__ z,
                                             const float* __restrict__ mw,
                                             float* __restrict__ out) {
  __shared__ float zs[16 * 256];
  __shared__ float tmp[4];
  int b = blockIdx.x >> 2, pt = blockIdx.x & 3, t = threadIdx.x;
  const float4* zb4 = (const float4*)(z + (size_t)b * 16384 + pt * 4096);
  for (int i = t; i < 1024; i += 256) ((float4*)zs)[i] = zb4[i];
  __syncthreads();

  const float4* m4 = (const float4*)mw;
  float4 acc[16];
#pragma unroll
  for (int pp = 0; pp < 16; ++pp) acc[pp] = make_float4(0.f, 0.f, 0.f, 0.f);

#pragma unroll 2
  for (int k4 = 0; k4 < 64; ++k4) {
    float4 w0 = m4[(4 * k4 + 0) * 256 + t];
    float4 w1 = m4[(4 * k4 + 1) * 256 + t];
    float4 w2 = m4[(4 * k4 + 2) * 256 + t];
    float4 w3 = m4[(4 * k4 + 3) * 256 + t];
#pragma unroll
    for (int pp = 0; pp < 16; ++pp) {
      float4 zv = *(const float4*)&zs[pp * 256 + k4 * 4];
      fma4(acc[pp], zv.x, w0);
      fma4(acc[pp], zv.y, w1);
      fma4(acc[pp], zv.z, w2);
      fma4(acc[pp], zv.w, w3);
    }
  }
  float total = 0.f;
#pragma unroll
  for (int pp = 0; pp < 16; ++pp) {
    float r;
    r = fmaxf(acc[pp].x, 0.f); total = fmaf(r, r, total);
    r = fmaxf(acc[pp].y, 0.f); total = fmaf(r, r, total);
    r = fmaxf(acc[pp].z, 0.f); total = fmaf(r, r, total);
    r = fmaxf(acc[pp].w, 0.f); total = fmaf(r, r, total);
  }
  float r = block_sum_256(total, tmp);
  if (t == 0) atomicAdd(out + b, -r);
}

__global__ __launch_bounds__(256) void k_attn(const float* __restrict__ z,
                                              const float* __restrict__ wq,
                                              const float* __restrict__ wk,
                                              float* __restrict__ out) {
  __shared__ float lds[8192];
  __shared__ float red[4];
  const int b = blockIdx.x >> 1, half = blockIdx.x & 1;
  const int t = threadIdx.x;
  const int lane = t & 63;
  const int w = __builtin_amdgcn_readfirstlane(t >> 6);
  const float4* zb4 = (const float4*)(z + (size_t)b * 16384);

  float qa[4][8], ka[4][8];
#pragma unroll
  for (int hh = 0; hh < 4; ++hh)
#pragma unroll
    for (int j = 0; j < 8; ++j) { qa[hh][j] = 0.f; ka[hh][j] = 0.f; }

  float4* lds4 = (float4*)lds;
  for (int dc = 0; dc < 2; ++dc) {
    __syncthreads();
    for (int i = t; i < 2048; i += 256) {
      int p = i >> 5, ld4 = i & 31;
      lds4[ld4 * 64 + (p ^ (ld4 & 7))] = zb4[p * 64 + dc * 32 + ld4];
    }
    __syncthreads();
#pragma unroll
    for (int hh = 0; hh < 4; ++hh) {
      int h = half * 4 + hh;
      const float* Wqb = wq + (size_t)h * 8192 + (size_t)(w * 8) * 256 + dc * 128;
      const float* Wkb = wk + (size_t)h * 8192 + (size_t)(w * 8) * 256 + dc * 128;
      for (int ld4 = 0; ld4 < 32; ++ld4) {
        float4 wv[8], kv[8];
#pragma unroll
        for (int j = 0; j < 8; ++j) {
          wv[j] = *(const float4*)(Wqb + j * 256 + ld4 * 4);
          kv[j] = *(const float4*)(Wkb + j * 256 + ld4 * 4);
        }
        float4 zv = lds4[ld4 * 64 + (lane ^ (ld4 & 7))];
#pragma unroll
        for (int j = 0; j < 8; ++j) {
          qa[hh][j] = fmaf(wv[j].x, zv.x, fmaf(wv[j].y, zv.y,
                      fmaf(wv[j].z, zv.z, fmaf(wv[j].w, zv.w, qa[hh][j]))));
          ka[hh][j] = fmaf(kv[j].x, zv.x, fmaf(kv[j].y, zv.y,
                      fmaf(kv[j].z, zv.z, fmaf(kv[j].w, zv.w, ka[hh][j]))));
        }
      }
    }
  }

  float* Qs = lds;
  float* Ks = lds + 2048;
  float lse = 0.f;
#pragma unroll
  for (int hh = 0; hh < 4; ++hh) {
    __syncthreads();
#pragma unroll
    for (int j = 0; j < 8; ++j) {
      Qs[(w * 8 + j) * 64 + lane] = qa[hh][j];
      Ks[(w * 8 + j) * 64 + lane] = ka[hh][j];
    }
    __syncthreads();
    float av[16];
#pragma unroll
    for (int mm = 0; mm < 16; ++mm) av[mm] = 0.f;
    for (int rr = 0; rr < 32; ++rr) {
      float kv = Ks[rr * 64 + lane];
      const float* qrow = &Qs[rr * 64 + w * 16];
      float4 q0 = *(const float4*)(qrow + 0);
      float4 q1 = *(const float4*)(qrow + 4);
      float4 q2 = *(const float4*)(qrow + 8);
      float4 q3 = *(const float4*)(qrow + 12);
      av[0]  = fmaf(q0.x, kv, av[0]);  av[1]  = fmaf(q0.y, kv, av[1]);
      av[2]  = fmaf(q0.z, kv, av[2]);  av[3]  = fmaf(q0.w, kv, av[3]);
      av[4]  = fmaf(q1.x, kv, av[4]);  av[5]  = fmaf(q1.y, kv, av[5]);
      av[6]  = fmaf(q1.z, kv, av[6]);  av[7]  = fmaf(q1.w, kv, av[7]);
      av[8]  = fmaf(q2.x, kv, av[8]);  av[9]  = fmaf(q2.y, kv, av[9]);
      av[10] = fmaf(q2.z, kv, av[10]); av[11] = fmaf(q2.w, kv, av[11]);
      av[12] = fmaf(q3.x, kv, av[12]); av[13] = fmaf(q3.y, kv, av[13]);
      av[14] = fmaf(q3.z, kv, av[14]); av[15] = fmaf(q3.w, kv, av[15]);
    }
#pragma unroll
    for (int mm = 0; mm < 16; ++mm) {
      float e = __expf(GAMMA * av[mm]);
#pragma unroll
      for (int off = 32; off; off >>= 1) e += __shfl_xor(e, off, 64);
      lse += __logf(e);
    }
  }
  if (lane == 0) red[w] = lse;
  __syncthreads();
  if (t == 0)
    atomicAdd(out + b, -(red[0] + red[1] + red[2] + red[3]) * (1.0f / GAMMA));
}

// ---------------------------------------------------------------------------
extern "C" void kernel_launch(void* const* d_in, const int* in_sizes, int n_in,
                              void* d_out, int out_size, void* d_ws,
                              size_t ws_size, hipStream_t stream) {
  (void)in_sizes; (void)n_in; (void)out_size;
  const float* x  = (const float*)d_in[0];
  const float* z  = (const float*)d_in[1];
  const float* ew = (const float*)d_in[2];
  const float* eb = (const float*)d_in[3];
  const float* vb = (const float*)d_in[4];
  const float* pb = (const float*)d_in[5];
  const float* mw = (const float*)d_in[6];
  const float* wq = (const float*)d_in[7];
  const float* wk = (const float*)d_in[8];
  float* out = (float*)d_out;

  const size_t Z_B  = (size_t)1024 * 64 * 256 * 2;  // 33.55 MB zb16
  const size_t MT_B = (size_t)1024 * 256 * 2;       // 0.52 MB mt16
  const size_t W_B  = (size_t)8 * 32 * 256 * 2;     // 128 KB each wq16/wk16
  const size_t EW_B = (size_t)256 * 192 * 2;        // 96 KB ew16
  const size_t FULL = Z_B + MT_B + 2 * W_B + EW_B;  // ~34.4 MB (no x16!)

  ushort* zb16 = (ushort*)d_ws;
  ushort* mt16 = (ushort*)((char*)d_ws + Z_B);
  ushort* wq16 = (ushort*)((char*)d_ws + Z_B + MT_B);
  ushort* wk16 = (ushort*)((char*)d_ws + Z_B + MT_B + W_B);
  ushort* ew16 = (ushort*)((char*)d_ws + Z_B + MT_B + 2 * W_B);

  if (ws_size >= FULL) {
    k_z_cvt<<<1024, 256, 0, stream>>>(z, eb, pb, out, zb16);
    k_cvt_weights<<<304, 256, 0, stream>>>(
        (const float4*)wq, (const float4*)wk, (const float4*)ew, mw,
        (ushort4*)wq16, (ushort4*)wk16, (ushort4*)ew16, mt16);
    k_enc_fused<<<1024, 256, 0, stream>>>(x, vb, ew16, zb16, out);
    k_mem_v3  <<<1024, 256, 0, stream>>>(zb16, mt16, out);
    k_attn_v3 <<<1024, 256, 0, stream>>>(zb16, wq16, wk16, out);
  } else {
    k_xz  <<<1024, 256, 0, stream>>>(x, z, vb, eb, pb, out);
    k_enc <<<1024, 256, 0, stream>>>(x, z, ew, out);
    k_mem <<<4096, 256, 0, stream>>>(z, mw, out);
    k_attn<<<2048, 256, 0, stream>>>(z, wq, wk, out);
  }
}

// Round 2
// 298.552 us; speedup vs baseline: 1.4589x; 1.4589x over previous
//
#include <hip/hip_runtime.h>
#include <hip/hip_bf16.h>

#define GAMMA 0.25f

// Shapes: B=1024, C=3, H=64, D=256, NP=64 (8x8 grid of 8x8 patches),
//         M=1024, NH=8, R=32, P=8.  fp32 in/out.  out[b] = quad - coupling.
//
// R2 theory: R1 counters showed k_attn_v3 at MfmaUtil 6% / VALUBusy 9% /
// HBM 1.8% — latency-bound on serialized per-wave L2 weight loads (VGPR=48:
// compiler kept ~2 loads in flight).  Fix applied to ALL MFMA kernels:
// (1) fragment-linear weight layouts: each B-fragment is a contiguous
//     [lane][8] 1KB wave-block -> one coalesced transaction per fragment;
// (2) explicit rotating register prefetch (depth 2-4, static indexing);
// (3) attn restored to grid 2048 (half-split) for block-level overlap.

typedef __attribute__((ext_vector_type(8))) short short8;  // 8 bf16 (4 VGPRs)
typedef __attribute__((ext_vector_type(4))) float f32x4;   // 4 fp32 acc

__device__ __forceinline__ float dot4(float4 a, float4 b) {
  return fmaf(a.x, b.x, fmaf(a.y, b.y, fmaf(a.z, b.z, a.w * b.w)));
}

__device__ __forceinline__ void fma4(float4& a, float s, float4 w) {
  a.x = fmaf(s, w.x, a.x); a.y = fmaf(s, w.y, a.y);
  a.z = fmaf(s, w.z, a.z); a.w = fmaf(s, w.w, a.w);
}

__device__ __forceinline__ ushort f2bf(float f) {
  __hip_bfloat16 h = __float2bfloat16(f);  // RNE
  return *reinterpret_cast<ushort*>(&h);
}

__device__ __forceinline__ float bf2f(ushort u) {
  union { unsigned int i; float f; } v;
  v.i = ((unsigned int)u) << 16;
  return v.f;
}

// 256-thread block sum; result valid on all threads.
__device__ __forceinline__ float block_sum_256(float v, float* tmp) {
#pragma unroll
  for (int off = 32; off; off >>= 1) v += __shfl_down(v, off, 64);
  int w = threadIdx.x >> 6;
  if ((threadIdx.x & 63) == 0) tmp[w] = v;
  __syncthreads();
  return tmp[0] + tmp[1] + tmp[2] + tmp[3];
}

// ---------------------------------------------------------------------------
// Kernel 1: z-only pass. quad_z - phi_bias - phi_pos, and z -> bf16 (zb16).
// ---------------------------------------------------------------------------
__global__ __launch_bounds__(256) void k_z_cvt(const float* __restrict__ z,
                                               const float* __restrict__ eb,
                                               const float* __restrict__ pb,
                                               float* __restrict__ out,
                                               ushort* __restrict__ zb16) {
  __shared__ float tmp[4];
  int b = blockIdx.x, t = threadIdx.x;
  const float4* zb = (const float4*)(z + (size_t)b * 16384);
  const float4* pb4 = (const float4*)pb;
  const float4* eb4 = (const float4*)eb;
  ushort4* z16o = (ushort4*)(zb16 + (size_t)b * 16384);
  float s = 0.f;
  for (int i = t; i < 4096; i += 256) {
    float4 zv = zb[i];
    float4 pv = pb4[i];
    float4 ev = eb4[i & 63];
    float4 c;
    c.x = pv.x + ev.x; c.y = pv.y + ev.y; c.z = pv.z + ev.z; c.w = pv.w + ev.w;
    s += 0.5f * dot4(zv, zv) - dot4(zv, c);
    ushort4 o;
    o.x = f2bf(zv.x); o.y = f2bf(zv.y); o.z = f2bf(zv.z); o.w = f2bf(zv.w);
    z16o[i] = o;
  }
  float r = block_sum_256(s, tmp);
  if (t == 0) out[b] = r;  // plain store: establishes out[b] for later atomics
}

// ---------------------------------------------------------------------------
// Weight conversion into FRAGMENT-LINEAR layouts (one launch, block ranges):
// [0,32)   wqf: [h][nt][ks][l][8]   frag = (h*2+nt)*8+ks, 128 frags x 1KB
// [32,64)  wkf: same
// [64,88)  ewf: [ks][ct][l][8]      frag = ks*16+ct,       96 frags x 1KB
// [88,216) mtf: [C][kc][l][8]       frag = C*8+kc,        512 frags x 1KB
// Each fragment is one contiguous 1KB wave-block: lane l holds 8 bf16
// B-elements (n = l&15, k = ks*32 + (l>>4)*8 + j) -> coalesced 16B/lane.
// ---------------------------------------------------------------------------
__global__ __launch_bounds__(256) void k_cvt_weights_v2(
    const float* __restrict__ wq, const float* __restrict__ wk,
    const float* __restrict__ ew, const float* __restrict__ mw,
    ushort* __restrict__ wqf, ushort* __restrict__ wkf,
    ushort* __restrict__ ewf, ushort* __restrict__ mtf) {
  int bid = blockIdx.x, t = threadIdx.x;
  ushort o[8];
  if (bid < 64) {
    const float* src = (bid < 32) ? wq : wk;
    ushort* dst = (bid < 32) ? wqf : wkf;
    int tid = (bid & 31) * 256 + t;  // 0..8191
    int frag = tid >> 6, l = tid & 63;
    int h = frag >> 4, nt = (frag >> 3) & 1, ks = frag & 7;
    const float* s = src + ((size_t)h * 32 + nt * 16 + (l & 15)) * 256 +
                     ks * 32 + (l >> 4) * 8;
#pragma unroll
    for (int i = 0; i < 8; ++i) o[i] = f2bf(s[i]);
    *(ushort4*)(dst + (size_t)tid * 8) = *(ushort4*)&o[0];
    *(ushort4*)(dst + (size_t)tid * 8 + 4) = *(ushort4*)&o[4];
  } else if (bid < 88) {
    int tid = (bid - 64) * 256 + t;  // 0..6143
    int frag = tid >> 6, l = tid & 63;
    int ks = frag >> 4, ct = frag & 15;
    const float* s = ew + ((size_t)ct * 16 + (l & 15)) * 192 + ks * 32 +
                     (l >> 4) * 8;
#pragma unroll
    for (int i = 0; i < 8; ++i) o[i] = f2bf(s[i]);
    *(ushort4*)(ewf + (size_t)tid * 8) = *(ushort4*)&o[0];
    *(ushort4*)(ewf + (size_t)tid * 8 + 4) = *(ushort4*)&o[4];
  } else {
    int tid = (bid - 88) * 256 + t;  // 0..32767
    int frag = tid >> 6, l = tid & 63;
    int C = frag >> 3, kc = frag & 7;
    int k0 = kc * 32 + (l >> 4) * 8, col = C * 16 + (l & 15);
#pragma unroll
    for (int i = 0; i < 8; ++i) o[i] = f2bf(mw[(size_t)(k0 + i) * 1024 + col]);
    *(ushort4*)(mtf + (size_t)tid * 8) = *(ushort4*)&o[0];
    *(ushort4*)(mtf + (size_t)tid * 8 + 4) = *(ushort4*)&o[4];
  }
}

// ---------------------------------------------------------------------------
// Kernel 2 (fused): quad_x - phi_vis - phi_enc.  x fp32 read once, staged to
// LDS as bf16; B-frags from ewf fragment-linear with depth-4 rolling
// register prefetch (96 fragments in iteration order f = ks*16+ct).
// ---------------------------------------------------------------------------
__global__ __launch_bounds__(256) void k_enc_v2(
    const float* __restrict__ x, const float* __restrict__ vb,
    const ushort* __restrict__ ewf, const ushort* __restrict__ zb16,
    float* __restrict__ out) {
  __shared__ ushort xs[12288];  // 24 KB: x[b] bf16, original NCHW layout
  __shared__ float tmp[4];
  const int b = blockIdx.x, t = threadIdx.x, l = t & 63, w = t >> 6;
  const int q = l >> 4, m = l & 15;

  const float4* xb = (const float4*)(x + (size_t)b * 12288);
  const float4* vb4 = (const float4*)vb;
  ushort4* xs4 = (ushort4*)xs;
  float s = 0.f;
  for (int i = t; i < 3072; i += 256) {
    float4 xv = xb[i];
    float4 bv = vb4[i];
    s += 0.5f * dot4(xv, xv) - dot4(bv, xv);
    ushort4 o;
    o.x = f2bf(xv.x); o.y = f2bf(xv.y); o.z = f2bf(xv.z); o.w = f2bf(xv.w);
    xs4[i] = o;
  }
  __syncthreads();

  const int p = 16 * w + m, gi = p >> 3, gj = p & 7;
  short8 a[6];
#pragma unroll
  for (int ks = 0; ks < 6; ++ks) {
    int k0 = ks * 32 + q * 8;
    int c = k0 >> 6, ii = (k0 & 63) >> 3;
    a[ks] = *(const short8*)(xs + c * 4096 + (gi * 8 + ii) * 64 + gj * 8);
  }

  f32x4 acc[16];
#pragma unroll
  for (int ct = 0; ct < 16; ++ct) acc[ct] = f32x4{0.f, 0.f, 0.f, 0.f};

  const ushort* Ep = ewf + (size_t)l * 8;
  short8 fb[4];
#pragma unroll
  for (int i = 0; i < 4; ++i) fb[i] = *(const short8*)(Ep + i * 512);
#pragma unroll
  for (int f = 0; f < 96; ++f) {
    const int ks = f >> 4, ct = f & 15;
    acc[ct] = __builtin_amdgcn_mfma_f32_16x16x32_bf16(a[ks], fb[f & 3],
                                                      acc[ct], 0, 0, 0);
    if (f < 92) fb[f & 3] = *(const short8*)(Ep + (size_t)(f + 4) * 512);
  }

  const ushort* zrow = zb16 + (size_t)b * 16384;
#pragma unroll
  for (int ct = 0; ct < 16; ++ct) {
#pragma unroll
    for (int reg = 0; reg < 4; ++reg) {
      int pp = 16 * w + 4 * q + reg;
      s -= acc[ct][reg] * bf2f(zrow[pp * 256 + 16 * ct + m]);
    }
  }
  float r = block_sum_256(s, tmp);
  if (t == 0) atomicAdd(out + b, r);  // += quad_x - phi_vis - phi_enc
}

// ---------------------------------------------------------------------------
// Kernel 3: phi_mem.  One block per b; wave w owns cols C = ct*16+w*4+c.
// B-frags from mtf fragment-linear with depth-2 rotating prefetch over kc.
// ---------------------------------------------------------------------------
__global__ __launch_bounds__(256) void k_mem_v4(const ushort* __restrict__ zb,
                                                const ushort* __restrict__ mtf,
                                                float* __restrict__ out) {
  __shared__ ushort zf[2048 * 8];  // 32 KB: z[b] fragment-ordered [w2][ks][l]
  __shared__ float tmp[4];
  const int t = threadIdx.x, l = t & 63, w = t >> 6;
  const int b = blockIdx.x;

#pragma unroll
  for (int j = 0; j < 8; ++j) {
    int i = t + j * 256;
    int l2 = i & 63, ks = (i >> 6) & 7, w2 = i >> 9;
    short8 v = *(const short8*)(zb + ((size_t)b * 64 + 16 * w2 + (l2 & 15)) * 256
                                + ks * 32 + (l2 >> 4) * 8);
    *(short8*)(zf + (size_t)i * 8) = v;
  }
  __syncthreads();

  float s = 0.f;
#pragma unroll 1
  for (int ct = 0; ct < 4; ++ct) {
    const ushort* Bb = mtf + ((size_t)(ct * 16 + w * 4) * 8) * 512 + (size_t)l * 8;
    short8 fb[2][4];
#pragma unroll
    for (int c = 0; c < 4; ++c) fb[0][c] = *(const short8*)(Bb + (c * 8 + 0) * 512);
#pragma unroll
    for (int c = 0; c < 4; ++c) fb[1][c] = *(const short8*)(Bb + (c * 8 + 1) * 512);

    f32x4 acc[4][4];
#pragma unroll
    for (int r = 0; r < 4; ++r)
#pragma unroll
      for (int c = 0; c < 4; ++c) acc[r][c] = f32x4{0.f, 0.f, 0.f, 0.f};

#pragma unroll
    for (int kc = 0; kc < 8; ++kc) {
      const int cur = kc & 1;
      short8 a4[4];
#pragma unroll
      for (int r = 0; r < 4; ++r)
        a4[r] = *(const short8*)(zf + (size_t)((r * 8 + kc) * 64 + l) * 8);
#pragma unroll
      for (int r = 0; r < 4; ++r)
#pragma unroll
        for (int c = 0; c < 4; ++c)
          acc[r][c] = __builtin_amdgcn_mfma_f32_16x16x32_bf16(a4[r], fb[cur][c],
                                                              acc[r][c], 0, 0, 0);
      if (kc < 6) {
#pragma unroll
        for (int c = 0; c < 4; ++c)
          fb[cur][c] = *(const short8*)(Bb + (c * 8 + kc + 2) * 512);
      }
    }
#pragma unroll
    for (int r = 0; r < 4; ++r)
#pragma unroll
      for (int c = 0; c < 4; ++c)
#pragma unroll
        for (int e = 0; e < 4; ++e) {
          float rr = fmaxf(acc[r][c][e], 0.f);
          s = fmaf(rr, rr, s);
        }
  }
  float r = block_sum_256(s, tmp);
  if (t == 0) atomicAdd(out + b, -r);
}

// ---------------------------------------------------------------------------
// Kernel 4: phi_att.  Grid 2048 (half-split: 4 heads/block — block-level
// overlap restored per R1 counters).  B-frags from wqf/wkf fragment-linear
// with depth-2 rotating prefetch.  Phase 2 unchanged (verified).
// ---------------------------------------------------------------------------
__global__ __launch_bounds__(256) void k_attn_v4(
    const ushort* __restrict__ zb, const ushort* __restrict__ wqf,
    const ushort* __restrict__ wkf, float* __restrict__ out) {
  __shared__ ushort Qb[64 * 40];  // one head: [p][r], stride 40 halfwords
  __shared__ ushort Kb[64 * 40];
  __shared__ float tmp[4];
  const int t = threadIdx.x, l = t & 63, w = t >> 6;
  const int b = blockIdx.x >> 1, half = blockIdx.x & 1;
  const int q = l >> 4, m = l & 15;

  // A-fragments of z[b] for m-tile w: reused across 4 heads and Q/K.
  const ushort* Az = zb + ((size_t)b * 64 + 16 * w + m) * 256 + q * 8;
  short8 a[8];
#pragma unroll
  for (int ks = 0; ks < 8; ++ks) a[ks] = *(const short8*)(Az + ks * 32);

  float part = 0.f;
  for (int hh = 0; hh < 4; ++hh) {
    const int h = half * 4 + hh;
    const ushort* Bq = wqf + (size_t)h * 8192 + (size_t)l * 8;
    const ushort* Bk = wkf + (size_t)h * 8192 + (size_t)l * 8;
    short8 fq0[2], fq1[2], fk0[2], fk1[2];
    fq0[0] = *(const short8*)(Bq + 0 * 512);
    fq1[0] = *(const short8*)(Bq + 8 * 512);
    fk0[0] = *(const short8*)(Bk + 0 * 512);
    fk1[0] = *(const short8*)(Bk + 8 * 512);
    fq0[1] = *(const short8*)(Bq + 1 * 512);
    fq1[1] = *(const short8*)(Bq + 9 * 512);
    fk0[1] = *(const short8*)(Bk + 1 * 512);
    fk1[1] = *(const short8*)(Bk + 9 * 512);

    f32x4 accq0 = f32x4{0.f, 0.f, 0.f, 0.f}, accq1 = accq0;
    f32x4 acck0 = accq0, acck1 = accq0;
#pragma unroll
    for (int ks = 0; ks < 8; ++ks) {
      const int cur = ks & 1;
      accq0 = __builtin_amdgcn_mfma_f32_16x16x32_bf16(a[ks], fq0[cur], accq0, 0, 0, 0);
      accq1 = __builtin_amdgcn_mfma_f32_16x16x32_bf16(a[ks], fq1[cur], accq1, 0, 0, 0);
      acck0 = __builtin_amdgcn_mfma_f32_16x16x32_bf16(a[ks], fk0[cur], acck0, 0, 0, 0);
      acck1 = __builtin_amdgcn_mfma_f32_16x16x32_bf16(a[ks], fk1[cur], acck1, 0, 0, 0);
      if (ks < 6) {
        fq0[cur] = *(const short8*)(Bq + (ks + 2) * 512);
        fq1[cur] = *(const short8*)(Bq + (10 + ks) * 512);
        fk0[cur] = *(const short8*)(Bk + (ks + 2) * 512);
        fk1[cur] = *(const short8*)(Bk + (10 + ks) * 512);
      }
    }
    // D (row = 16w+4q+reg, col = r) -> bf16 -> LDS (stride 40: 2-way only).
    const int rowbase = (16 * w + 4 * q) * 40;
#pragma unroll
    for (int reg = 0; reg < 4; ++reg) {
      Qb[rowbase + reg * 40 + m]      = f2bf(accq0[reg]);
      Qb[rowbase + reg * 40 + 16 + m] = f2bf(accq1[reg]);
      Kb[rowbase + reg * 40 + m]      = f2bf(acck0[reg]);
      Kb[rowbase + reg * 40 + 16 + m] = f2bf(acck1[reg]);
    }
    __syncthreads();

    // Phase 2: A-frag rows 16w+m, k=r=q*8..+7; B-frags from Kb per n-tile.
    short8 qa = *(const short8*)&Qb[(16 * w + m) * 40 + q * 8];
    f32x4 acc[4];
#pragma unroll
    for (int nt = 0; nt < 4; ++nt) {
      short8 kb = *(const short8*)&Kb[(16 * nt + m) * 40 + q * 8];
      acc[nt] = __builtin_amdgcn_mfma_f32_16x16x32_bf16(
          qa, kb, f32x4{0.f, 0.f, 0.f, 0.f}, 0, 0, 0);
    }
#pragma unroll
    for (int reg = 0; reg < 4; ++reg) {
      float e = __expf(GAMMA * acc[0][reg]) + __expf(GAMMA * acc[1][reg]) +
                __expf(GAMMA * acc[2][reg]) + __expf(GAMMA * acc[3][reg]);
      e += __shfl_xor(e, 1, 64);
      e += __shfl_xor(e, 2, 64);
      e += __shfl_xor(e, 4, 64);
      e += __shfl_xor(e, 8, 64);
      part += (m == 0) ? __logf(e) : 0.f;  // one log per row 16w+4q+reg
    }
    __syncthreads();  // all Qb/Kb reads done before next head's writes
  }
  float tot = block_sum_256(part, tmp);
  if (t == 0) atomicAdd(out + b, -tot * (1.0f / GAMMA));
}

// ---------------------------------------------------------------------------
// Fallback kernels (no-workspace tier).
// ---------------------------------------------------------------------------
__global__ __launch_bounds__(256) void k_xz(const float* __restrict__ x,
                                            const float* __restrict__ z,
                                            const float* __restrict__ vb,
                                            const float* __restrict__ eb,
                                            const float* __restrict__ pb,
                                            float* __restrict__ out) {
  __shared__ float tmp[4];
  int b = blockIdx.x, t = threadIdx.x;
  const float4* xb = (const float4*)(x + (size_t)b * 12288);
  const float4* vb4 = (const float4*)vb;
  float s = 0.f;
  for (int i = t; i < 3072; i += 256) {
    float4 xv = xb[i];
    float4 bv = vb4[i];
    s += 0.5f * dot4(xv, xv) - dot4(bv, xv);
  }
  const float4* zb = (const float4*)(z + (size_t)b * 16384);
  const float4* pb4 = (const float4*)pb;
  const float4* eb4 = (const float4*)eb;
  for (int i = t; i < 4096; i += 256) {
    float4 zv = zb[i];
    float4 pv = pb4[i];
    float4 ev = eb4[i & 63];
    float4 c;
    c.x = pv.x + ev.x; c.y = pv.y + ev.y; c.z = pv.z + ev.z; c.w = pv.w + ev.w;
    s += 0.5f * dot4(zv, zv) - dot4(zv, c);
  }
  float r = block_sum_256(s, tmp);
  if (t == 0) out[b] = r;
}

__global__ __launch_bounds__(256) void k_enc(const float* __restrict__ x,
                                             const float* __restrict__ z,
                                             const float* __restrict__ ew,
                                             float* __restrict__ out) {
  __shared__ float xs[12288];
  __shared__ float tmp[4];
  int b = blockIdx.x, t = threadIdx.x;
  const float4* xb4 = (const float4*)(x + (size_t)b * 12288);
  for (int i = t; i < 3072; i += 256) ((float4*)xs)[i] = xb4[i];
  __syncthreads();

  float acc[64];
#pragma unroll
  for (int p = 0; p < 64; ++p) acc[p] = 0.f;

  for (int k4 = 0; k4 < 48; ++k4) {
    float4 wv = *(const float4*)(ew + (size_t)t * 192 + k4 * 4);
    int c = k4 >> 4;
    int ii = (k4 >> 1) & 7;
    int jh = (k4 & 1) * 4;
    const float* base = xs + c * 4096 + ii * 64 + jh;
#pragma unroll
    for (int p = 0; p < 64; ++p) {
      float4 pv = *(const float4*)(base + (p >> 3) * 512 + (p & 7) * 8);
      acc[p] = fmaf(wv.x, pv.x,
               fmaf(wv.y, pv.y, fmaf(wv.z, pv.z, fmaf(wv.w, pv.w, acc[p]))));
    }
  }
  const float* zb = z + (size_t)b * 16384;
  float s = 0.f;
#pragma unroll
  for (int p = 0; p < 64; ++p) s += acc[p] * zb[p * 256 + t];
  float r = block_sum_256(s, tmp);
  if (t == 0) atomicAdd(out + b, -r);
}

__global__ __launch_bounds__(256) void k_mem(const float* __restrict__ z,
                                             const float* __restrict__ mw,
                                             float* __restrict__ out) {
  __shared__ float zs[16 * 256];
  __shared__ float tmp[4];
  int b = blockIdx.x >> 2, pt = blockIdx.x & 3, t = threadIdx.x;
  const float4* zb4 = (const float4*)(z + (size_t)b * 16384 + pt * 4096);
  for (int i = t; i < 1024; i += 256) ((float4*)zs)[i] = zb4[i];
  __syncthreads();

  const float4* m4 = (const float4*)mw;
  float4 acc[16];
#pragma unroll
  for (int pp = 0; pp < 16; ++pp) acc[pp] = make_float4(0.f, 0.f, 0.f, 0.f);

#pragma unroll 2
  for (int k4 = 0; k4 < 64; ++k4) {
    float4 w0 = m4[(4 * k4 + 0) * 256 + t];
    float4 w1 = m4[(4 * k4 + 1) * 256 + t];
    float4 w2 = m4[(4 * k4 + 2) * 256 + t];
    float4 w3 = m4[(4 * k4 + 3) * 256 + t];
#pragma unroll
    for (int pp = 0; pp < 16; ++pp) {
      float4 zv = *(const float4*)&zs[pp * 256 + k4 * 4];
      fma4(acc[pp], zv.x, w0);
      fma4(acc[pp], zv.y, w1);
      fma4(acc[pp], zv.z, w2);
      fma4(acc[pp], zv.w, w3);
    }
  }
  float total = 0.f;
#pragma unroll
  for (int pp = 0; pp < 16; ++pp) {
    float r;
    r = fmaxf(acc[pp].x, 0.f); total = fmaf(r, r, total);
    r = fmaxf(acc[pp].y, 0.f); total = fmaf(r, r, total);
    r = fmaxf(acc[pp].z, 0.f); total = fmaf(r, r, total);
    r = fmaxf(acc[pp].w, 0.f); total = fmaf(r, r, total);
  }
  float r = block_sum_256(total, tmp);
  if (t == 0) atomicAdd(out + b, -r);
}

__global__ __launch_bounds__(256) void k_attn(const float* __restrict__ z,
                                              const float* __restrict__ wq,
                                              const float* __restrict__ wk,
                                              float* __restrict__ out) {
  __shared__ float lds[8192];
  __shared__ float red[4];
  const int b = blockIdx.x >> 1, half = blockIdx.x & 1;
  const int t = threadIdx.x;
  const int lane = t & 63;
  const int w = __builtin_amdgcn_readfirstlane(t >> 6);
  const float4* zb4 = (const float4*)(z + (size_t)b * 16384);

  float qa[4][8], ka[4][8];
#pragma unroll
  for (int hh = 0; hh < 4; ++hh)
#pragma unroll
    for (int j = 0; j < 8; ++j) { qa[hh][j] = 0.f; ka[hh][j] = 0.f; }

  float4* lds4 = (float4*)lds;
  for (int dc = 0; dc < 2; ++dc) {
    __syncthreads();
    for (int i = t; i < 2048; i += 256) {
      int p = i >> 5, ld4 = i & 31;
      lds4[ld4 * 64 + (p ^ (ld4 & 7))] = zb4[p * 64 + dc * 32 + ld4];
    }
    __syncthreads();
#pragma unroll
    for (int hh = 0; hh < 4; ++hh) {
      int h = half * 4 + hh;
      const float* Wqb = wq + (size_t)h * 8192 + (size_t)(w * 8) * 256 + dc * 128;
      const float* Wkb = wk + (size_t)h * 8192 + (size_t)(w * 8) * 256 + dc * 128;
      for (int ld4 = 0; ld4 < 32; ++ld4) {
        float4 wv[8], kv[8];
#pragma unroll
        for (int j = 0; j < 8; ++j) {
          wv[j] = *(const float4*)(Wqb + j * 256 + ld4 * 4);
          kv[j] = *(const float4*)(Wkb + j * 256 + ld4 * 4);
        }
        float4 zv = lds4[ld4 * 64 + (lane ^ (ld4 & 7))];
#pragma unroll
        for (int j = 0; j < 8; ++j) {
          qa[hh][j] = fmaf(wv[j].x, zv.x, fmaf(wv[j].y, zv.y,
                      fmaf(wv[j].z, zv.z, fmaf(wv[j].w, zv.w, qa[hh][j]))));
          ka[hh][j] = fmaf(kv[j].x, zv.x, fmaf(kv[j].y, zv.y,
                      fmaf(kv[j].z, zv.z, fmaf(kv[j].w, zv.w, ka[hh][j]))));
        }
      }
    }
  }

  float* Qs = lds;
  float* Ks = lds + 2048;
  float lse = 0.f;
#pragma unroll
  for (int hh = 0; hh < 4; ++hh) {
    __syncthreads();
#pragma unroll
    for (int j = 0; j < 8; ++j) {
      Qs[(w * 8 + j) * 64 + lane] = qa[hh][j];
      Ks[(w * 8 + j) * 64 + lane] = ka[hh][j];
    }
    __syncthreads();
    float av[16];
#pragma unroll
    for (int mm = 0; mm < 16; ++mm) av[mm] = 0.f;
    for (int rr = 0; rr < 32; ++rr) {
      float kv = Ks[rr * 64 + lane];
      const float* qrow = &Qs[rr * 64 + w * 16];
      float4 q0 = *(const float4*)(qrow + 0);
      float4 q1 = *(const float4*)(qrow + 4);
      float4 q2 = *(const float4*)(qrow + 8);
      float4 q3 = *(const float4*)(qrow + 12);
      av[0]  = fmaf(q0.x, kv, av[0]);  av[1]  = fmaf(q0.y, kv, av[1]);
      av[2]  = fmaf(q0.z, kv, av[2]);  av[3]  = fmaf(q0.w, kv, av[3]);
      av[4]  = fmaf(q1.x, kv, av[4]);  av[5]  = fmaf(q1.y, kv, av[5]);
      av[6]  = fmaf(q1.z, kv, av[6]);  av[7]  = fmaf(q1.w, kv, av[7]);
      av[8]  = fmaf(q2.x, kv, av[8]);  av[9]  = fmaf(q2.y, kv, av[9]);
      av[10] = fmaf(q2.z, kv, av[10]); av[11] = fmaf(q2.w, kv, av[11]);
      av[12] = fmaf(q3.x, kv, av[12]); av[13] = fmaf(q3.y, kv, av[13]);
      av[14] = fmaf(q3.z, kv, av[14]); av[15] = fmaf(q3.w, kv, av[15]);
    }
#pragma unroll
    for (int mm = 0; mm < 16; ++mm) {
      float e = __expf(GAMMA * av[mm]);
#pragma unroll
      for (int off = 32; off; off >>= 1) e += __shfl_xor(e, off, 64);
      lse += __logf(e);
    }
  }
  if (lane == 0) red[w] = lse;
  __syncthreads();
  if (t == 0)
    atomicAdd(out + b, -(red[0] + red[1] + red[2] + red[3]) * (1.0f / GAMMA));
}

// ---------------------------------------------------------------------------
extern "C" void kernel_launch(void* const* d_in, const int* in_sizes, int n_in,
                              void* d_out, int out_size, void* d_ws,
                              size_t ws_size, hipStream_t stream) {
  (void)in_sizes; (void)n_in; (void)out_size;
  const float* x  = (const float*)d_in[0];
  const float* z  = (const float*)d_in[1];
  const float* ew = (const float*)d_in[2];
  const float* eb = (const float*)d_in[3];
  const float* vb = (const float*)d_in[4];
  const float* pb = (const float*)d_in[5];
  const float* mw = (const float*)d_in[6];
  const float* wq = (const float*)d_in[7];
  const float* wk = (const float*)d_in[8];
  float* out = (float*)d_out;

  const size_t Z_B  = (size_t)1024 * 64 * 256 * 2;  // 33.55 MB zb16
  const size_t MT_B = (size_t)1024 * 256 * 2;       // 0.52 MB mtf
  const size_t W_B  = (size_t)8 * 32 * 256 * 2;     // 128 KB each wqf/wkf
  const size_t EW_B = (size_t)256 * 192 * 2;        // 96 KB ewf
  const size_t FULL = Z_B + MT_B + 2 * W_B + EW_B;  // ~34.4 MB

  ushort* zb16 = (ushort*)d_ws;
  ushort* mtf  = (ushort*)((char*)d_ws + Z_B);
  ushort* wqf  = (ushort*)((char*)d_ws + Z_B + MT_B);
  ushort* wkf  = (ushort*)((char*)d_ws + Z_B + MT_B + W_B);
  ushort* ewf  = (ushort*)((char*)d_ws + Z_B + MT_B + 2 * W_B);

  if (ws_size >= FULL) {
    k_z_cvt<<<1024, 256, 0, stream>>>(z, eb, pb, out, zb16);
    k_cvt_weights_v2<<<216, 256, 0, stream>>>(wq, wk, ew, mw,
                                              wqf, wkf, ewf, mtf);
    k_enc_v2 <<<1024, 256, 0, stream>>>(x, vb, ewf, zb16, out);
    k_mem_v4 <<<1024, 256, 0, stream>>>(zb16, mtf, out);
    k_attn_v4<<<2048, 256, 0, stream>>>(zb16, wqf, wkf, out);
  } else {
    k_xz  <<<1024, 256, 0, stream>>>(x, z, vb, eb, pb, out);
    k_enc <<<1024, 256, 0, stream>>>(x, z, ew, out);
    k_mem <<<4096, 256, 0, stream>>>(z, mw, out);
    k_attn<<<2048, 256, 0, stream>>>(z, wq, wk, out);
  }
}

// Round 3
// 261.166 us; speedup vs baseline: 1.6677x; 1.1432x over previous
//
#include <hip/hip_runtime.h>
#include <hip/hip_bf16.h>

#define GAMMA 0.25f

// Shapes: B=1024, C=3, H=64, D=256, NP=64 (8x8 grid of 8x8 patches),
//         M=1024, NH=8, R=32, P=8.  fp32 in/out.  out[b] = quad - coupling.
//
// R3: enc recomputed as sum_{p,k} x[p,k]*(z W)[p,k] -> epilogue reads x from
// LDS (no scattered global u16 loads), B-prefetch depth 8.  z_cvt and mem
// split to grid 2048.  attn: depth-3 rotating prefetch pipelined ACROSS
// heads over raw s_barrier+lgkmcnt(0) (global->reg loads stay in flight).
// out[] is memset to 0 and every kernel atomicAdds.

typedef __attribute__((ext_vector_type(8))) short short8;  // 8 bf16 (4 VGPRs)
typedef __attribute__((ext_vector_type(4))) float f32x4;   // 4 fp32 acc

__device__ __forceinline__ float dot4(float4 a, float4 b) {
  return fmaf(a.x, b.x, fmaf(a.y, b.y, fmaf(a.z, b.z, a.w * b.w)));
}

__device__ __forceinline__ void fma4(float4& a, float s, float4 w) {
  a.x = fmaf(s, w.x, a.x); a.y = fmaf(s, w.y, a.y);
  a.z = fmaf(s, w.z, a.z); a.w = fmaf(s, w.w, a.w);
}

__device__ __forceinline__ ushort f2bf(float f) {
  __hip_bfloat16 h = __float2bfloat16(f);  // RNE
  return *reinterpret_cast<ushort*>(&h);
}

__device__ __forceinline__ float bf2f(ushort u) {
  union { unsigned int i; float f; } v;
  v.i = ((unsigned int)u) << 16;
  return v.f;
}

// LDS-only barrier: drains LDS ops but lets global->register loads stay in
// flight across it (unlike __syncthreads, which drains vmcnt(0)).
__device__ __forceinline__ void bar_lds() {
  asm volatile("s_waitcnt lgkmcnt(0)" ::: "memory");
  __builtin_amdgcn_s_barrier();
  asm volatile("" ::: "memory");
}

// 256-thread block sum; result valid on all threads.
__device__ __forceinline__ float block_sum_256(float v, float* tmp) {
#pragma unroll
  for (int off = 32; off; off >>= 1) v += __shfl_down(v, off, 64);
  int w = threadIdx.x >> 6;
  if ((threadIdx.x & 63) == 0) tmp[w] = v;
  __syncthreads();
  return tmp[0] + tmp[1] + tmp[2] + tmp[3];
}

// ---------------------------------------------------------------------------
// Kernel 1: z pass, grid 2048 (2 blocks per b for BW saturation).
// quad_z - phi_bias - phi_pos, and z -> bf16 (zb16).  atomicAdd onto 0.
// ---------------------------------------------------------------------------
__global__ __launch_bounds__(256) void k_z_cvt2(const float* __restrict__ z,
                                                const float* __restrict__ eb,
                                                const float* __restrict__ pb,
                                                float* __restrict__ out,
                                                ushort* __restrict__ zb16) {
  __shared__ float tmp[4];
  int bid = blockIdx.x, b = bid >> 1, hz = bid & 1, t = threadIdx.x;
  const float4* zb = (const float4*)(z + (size_t)b * 16384);
  const float4* pb4 = (const float4*)pb;
  const float4* eb4 = (const float4*)eb;
  ushort4* z16o = (ushort4*)(zb16 + (size_t)b * 16384);
  float s = 0.f;
  const int i0 = hz * 2048;
  for (int i = i0 + t; i < i0 + 2048; i += 256) {
    float4 zv = zb[i];
    float4 pv = pb4[i];
    float4 ev = eb4[i & 63];
    float4 c;
    c.x = pv.x + ev.x; c.y = pv.y + ev.y; c.z = pv.z + ev.z; c.w = pv.w + ev.w;
    s += 0.5f * dot4(zv, zv) - dot4(zv, c);
    ushort4 o;
    o.x = f2bf(zv.x); o.y = f2bf(zv.y); o.z = f2bf(zv.z); o.w = f2bf(zv.w);
    z16o[i] = o;
  }
  float r = block_sum_256(s, tmp);
  if (t == 0) atomicAdd(out + b, r);
}

// ---------------------------------------------------------------------------
// Weight conversion into FRAGMENT-LINEAR layouts (one launch, block ranges):
// [0,32)   wqf: frag=(h*2+nt)*8+ks, B[k][n]=W[h][nt*16+n][k]  128 frags
// [32,64)  wkf: same
// [64,88)  ewt: frag=ks*12+ct, B[d][k]=ew[d][ct*16+k&15]      96 frags (W^T!)
// [88,216) mtf: frag=C*8+kc,   B[k][m]=mw[k][C*16+m]          512 frags
// Each fragment = contiguous [l][8] 1KB wave-block (coalesced 16B/lane).
// ---------------------------------------------------------------------------
__global__ __launch_bounds__(256) void k_cvt_weights_v3(
    const float* __restrict__ wq, const float* __restrict__ wk,
    const float* __restrict__ ew, const float* __restrict__ mw,
    ushort* __restrict__ wqf, ushort* __restrict__ wkf,
    ushort* __restrict__ ewt, ushort* __restrict__ mtf) {
  int bid = blockIdx.x, t = threadIdx.x;
  ushort o[8];
  if (bid < 64) {
    const float* src = (bid < 32) ? wq : wk;
    ushort* dst = (bid < 32) ? wqf : wkf;
    int tid = (bid & 31) * 256 + t;  // 0..8191
    int frag = tid >> 6, l = tid & 63;
    int h = frag >> 4, nt = (frag >> 3) & 1, ks = frag & 7;
    const float* s = src + ((size_t)h * 32 + nt * 16 + (l & 15)) * 256 +
                     ks * 32 + (l >> 4) * 8;
#pragma unroll
    for (int i = 0; i < 8; ++i) o[i] = f2bf(s[i]);
    *(ushort4*)(dst + (size_t)tid * 8) = *(ushort4*)&o[0];
    *(ushort4*)(dst + (size_t)tid * 8 + 4) = *(ushort4*)&o[4];
  } else if (bid < 88) {
    int tid = (bid - 64) * 256 + t;  // 0..6143
    int frag = tid >> 6, l = tid & 63;
    int ks = frag / 12, ct = frag % 12;
    // B = W^T: element (k_dim = d, col = k): ew[d*192 + k]
    const float* s = ew + (size_t)(ks * 32 + (l >> 4) * 8) * 192 +
                     ct * 16 + (l & 15);
#pragma unroll
    for (int i = 0; i < 8; ++i) o[i] = f2bf(s[(size_t)i * 192]);
    *(ushort4*)(ewt + (size_t)tid * 8) = *(ushort4*)&o[0];
    *(ushort4*)(ewt + (size_t)tid * 8 + 4) = *(ushort4*)&o[4];
  } else {
    int tid = (bid - 88) * 256 + t;  // 0..32767
    int frag = tid >> 6, l = tid & 63;
    int C = frag >> 3, kc = frag & 7;
    int k0 = kc * 32 + (l >> 4) * 8, col = C * 16 + (l & 15);
#pragma unroll
    for (int i = 0; i < 8; ++i) o[i] = f2bf(mw[(size_t)(k0 + i) * 1024 + col]);
    *(ushort4*)(mtf + (size_t)tid * 8) = *(ushort4*)&o[0];
    *(ushort4*)(mtf + (size_t)tid * 8 + 4) = *(ushort4*)&o[4];
  }
}

// ---------------------------------------------------------------------------
// Kernel 2: quad_x - phi_vis - phi_enc via Y = z·W^T:  phi_enc =
// sum_{p,k} xpatch[p,k] * Y[p,k].  A = z-frags (coalesced-ish zb16 reads,
// issued before x staging), B = ewt (L2-resident, depth-8 prefetch),
// epilogue = 48 LDS u16 reads of xs per thread (no scattered global loads).
// ---------------------------------------------------------------------------
__global__ __launch_bounds__(256) void k_enc_v3(
    const float* __restrict__ x, const float* __restrict__ vb,
    const ushort* __restrict__ ewt, const ushort* __restrict__ zb16,
    float* __restrict__ out) {
  __shared__ ushort xs[12288];  // 24 KB: x[b] bf16, original NCHW layout
  __shared__ float tmp[4];
  const int b = blockIdx.x, t = threadIdx.x, l = t & 63, w = t >> 6;
  const int q = l >> 4, m = l & 15;

  // Issue z A-frag loads first (independent of x staging; overlap).
  const ushort* Az = zb16 + ((size_t)b * 64 + 16 * w + m) * 256 + q * 8;
  short8 a[8];
#pragma unroll
  for (int ks = 0; ks < 8; ++ks) a[ks] = *(const short8*)(Az + ks * 32);

  // Stage x -> bf16 LDS; accumulate quad_x - phi_vis in fp32.
  const float4* xb = (const float4*)(x + (size_t)b * 12288);
  const float4* vb4 = (const float4*)vb;
  ushort4* xs4 = (ushort4*)xs;
  float s = 0.f;
  for (int i = t; i < 3072; i += 256) {
    float4 xv = xb[i];
    float4 bv = vb4[i];
    s += 0.5f * dot4(xv, xv) - dot4(bv, xv);
    ushort4 o;
    o.x = f2bf(xv.x); o.y = f2bf(xv.y); o.z = f2bf(xv.z); o.w = f2bf(xv.w);
    xs4[i] = o;
  }
  __syncthreads();

  f32x4 acc[12];
#pragma unroll
  for (int ct = 0; ct < 12; ++ct) acc[ct] = f32x4{0.f, 0.f, 0.f, 0.f};

  const ushort* Ep = ewt + (size_t)l * 8;
  short8 fb[8];
#pragma unroll
  for (int i = 0; i < 8; ++i) fb[i] = *(const short8*)(Ep + i * 512);
#pragma unroll
  for (int f = 0; f < 96; ++f) {
    const int ks = f / 12, ct = f % 12;
    acc[ct] = __builtin_amdgcn_mfma_f32_16x16x32_bf16(a[ks], fb[f & 7],
                                                      acc[ct], 0, 0, 0);
    if (f < 88) fb[f & 7] = *(const short8*)(Ep + (size_t)(f + 8) * 512);
  }

  // Epilogue: D element (row p = 16w+4q+reg, col k = 16ct+m) * x[p,k] (LDS).
#pragma unroll
  for (int ct = 0; ct < 12; ++ct) {
#pragma unroll
    for (int reg = 0; reg < 4; ++reg) {
      const int p = 16 * w + 4 * q + reg, gi = p >> 3, gj = p & 7;
      const int k = ct * 16 + m, c = k >> 6, r2 = k & 63;
      const int ii = r2 >> 3, jj = r2 & 7;
      s -= acc[ct][reg] * bf2f(xs[c * 4096 + (gi * 8 + ii) * 64 + gj * 8 + jj]);
    }
  }
  float r = block_sum_256(s, tmp);
  if (t == 0) atomicAdd(out + b, r);  // += quad_x - phi_vis - phi_enc
}

// ---------------------------------------------------------------------------
// Kernel 3: phi_mem.  Grid 2048: block = (b, ct-pair).  zf staged once per
// block (zb16 read 2x total); B-frags mtf depth-2 rotating prefetch.
// ---------------------------------------------------------------------------
__global__ __launch_bounds__(256) void k_mem_v5(const ushort* __restrict__ zb,
                                                const ushort* __restrict__ mtf,
                                                float* __restrict__ out) {
  __shared__ ushort zf[2048 * 8];  // 32 KB: z[b] fragment-ordered [w2][ks][l]
  __shared__ float tmp[4];
  const int t = threadIdx.x, l = t & 63, w = t >> 6;
  const int b = blockIdx.x >> 1, cth = blockIdx.x & 1;

#pragma unroll
  for (int j = 0; j < 8; ++j) {
    int i = t + j * 256;
    int l2 = i & 63, ks = (i >> 6) & 7, w2 = i >> 9;
    short8 v = *(const short8*)(zb + ((size_t)b * 64 + 16 * w2 + (l2 & 15)) * 256
                                + ks * 32 + (l2 >> 4) * 8);
    *(short8*)(zf + (size_t)i * 8) = v;
  }
  __syncthreads();

  float s = 0.f;
#pragma unroll 1
  for (int ctl = 0; ctl < 2; ++ctl) {
    const int ct = cth * 2 + ctl;
    const ushort* Bb = mtf + ((size_t)(ct * 16 + w * 4) * 8) * 512 + (size_t)l * 8;
    short8 fb[2][4];
#pragma unroll
    for (int c = 0; c < 4; ++c) fb[0][c] = *(const short8*)(Bb + (c * 8 + 0) * 512);
#pragma unroll
    for (int c = 0; c < 4; ++c) fb[1][c] = *(const short8*)(Bb + (c * 8 + 1) * 512);

    f32x4 acc[4][4];
#pragma unroll
    for (int r = 0; r < 4; ++r)
#pragma unroll
      for (int c = 0; c < 4; ++c) acc[r][c] = f32x4{0.f, 0.f, 0.f, 0.f};

#pragma unroll
    for (int kc = 0; kc < 8; ++kc) {
      const int cur = kc & 1;
      short8 a4[4];
#pragma unroll
      for (int r = 0; r < 4; ++r)
        a4[r] = *(const short8*)(zf + (size_t)((r * 8 + kc) * 64 + l) * 8);
#pragma unroll
      for (int r = 0; r < 4; ++r)
#pragma unroll
        for (int c = 0; c < 4; ++c)
          acc[r][c] = __builtin_amdgcn_mfma_f32_16x16x32_bf16(a4[r], fb[cur][c],
                                                              acc[r][c], 0, 0, 0);
      if (kc < 6) {
#pragma unroll
        for (int c = 0; c < 4; ++c)
          fb[cur][c] = *(const short8*)(Bb + (c * 8 + kc + 2) * 512);
      }
    }
#pragma unroll
    for (int r = 0; r < 4; ++r)
#pragma unroll
      for (int c = 0; c < 4; ++c)
#pragma unroll
        for (int e = 0; e < 4; ++e) {
          float rr = fmaxf(acc[r][c][e], 0.f);
          s = fmaf(rr, rr, s);
        }
  }
  float r = block_sum_256(s, tmp);
  if (t == 0) atomicAdd(out + b, -r);
}

// ---------------------------------------------------------------------------
// Kernel 4: phi_att.  Grid 2048 (4 heads/block).  Depth-3 rotating prefetch
// pipelined ACROSS heads: W loads issued up to 3 steps ahead over the
// 32-step (4 heads x 8 ks) unrolled schedule; raw s_barrier + lgkmcnt(0)
// lets them stay in flight across the per-head phase boundaries.
// ---------------------------------------------------------------------------
__global__ __launch_bounds__(256) void k_attn_v5(
    const ushort* __restrict__ zb, const ushort* __restrict__ wqf,
    const ushort* __restrict__ wkf, float* __restrict__ out) {
  __shared__ ushort Qb[64 * 40];  // one head: [p][r], stride 40 halfwords
  __shared__ ushort Kb[64 * 40];
  __shared__ float tmp[4];
  const int t = threadIdx.x, l = t & 63, w = t >> 6;
  const int b = blockIdx.x >> 1, half = blockIdx.x & 1;
  const int q = l >> 4, m = l & 15;

  // A-fragments of z[b] for m-tile w: reused across 4 heads and Q/K.
  const ushort* Az = zb + ((size_t)b * 64 + 16 * w + m) * 256 + q * 8;
  short8 a[8];
#pragma unroll
  for (int ks = 0; ks < 8; ++ks) a[ks] = *(const short8*)(Az + ks * 32);

  const ushort* Wq0 = wqf + (size_t)(half * 4) * 8192 + (size_t)l * 8;
  const ushort* Wk0 = wkf + (size_t)(half * 4) * 8192 + (size_t)l * 8;

  short8 fq0[3], fq1[3], fk0[3], fk1[3];
#pragma unroll
  for (int i = 0; i < 3; ++i) {  // preload gs = 0,1,2 (head 0, ks 0..2)
    fq0[i] = *(const short8*)(Wq0 + i * 512);
    fq1[i] = *(const short8*)(Wq0 + (8 + i) * 512);
    fk0[i] = *(const short8*)(Wk0 + i * 512);
    fk1[i] = *(const short8*)(Wk0 + (8 + i) * 512);
  }

  float part = 0.f;
#pragma unroll
  for (int hh = 0; hh < 4; ++hh) {
    f32x4 accq0 = f32x4{0.f, 0.f, 0.f, 0.f}, accq1 = accq0;
    f32x4 acck0 = accq0, acck1 = accq0;
#pragma unroll
    for (int ks = 0; ks < 8; ++ks) {
      const int gs = hh * 8 + ks, cur = gs % 3;
      accq0 = __builtin_amdgcn_mfma_f32_16x16x32_bf16(a[ks], fq0[cur], accq0, 0, 0, 0);
      accq1 = __builtin_amdgcn_mfma_f32_16x16x32_bf16(a[ks], fq1[cur], accq1, 0, 0, 0);
      acck0 = __builtin_amdgcn_mfma_f32_16x16x32_bf16(a[ks], fk0[cur], acck0, 0, 0, 0);
      acck1 = __builtin_amdgcn_mfma_f32_16x16x32_bf16(a[ks], fk1[cur], acck1, 0, 0, 0);
      const int gn = gs + 3;
      if (gn < 32) {  // prefetch step gn (possibly next head) into slot gn%3
        const int hn = gn >> 3, ksn = gn & 7, sl = gn % 3;
        const ushort* Bqn = Wq0 + (size_t)hn * 8192;
        const ushort* Bkn = Wk0 + (size_t)hn * 8192;
        fq0[sl] = *(const short8*)(Bqn + ksn * 512);
        fq1[sl] = *(const short8*)(Bqn + (8 + ksn) * 512);
        fk0[sl] = *(const short8*)(Bkn + ksn * 512);
        fk1[sl] = *(const short8*)(Bkn + (8 + ksn) * 512);
      }
    }
    // D (row = 16w+4q+reg, col = r) -> bf16 -> LDS (stride 40: 2-way only).
    const int rowbase = (16 * w + 4 * q) * 40;
#pragma unroll
    for (int reg = 0; reg < 4; ++reg) {
      Qb[rowbase + reg * 40 + m]      = f2bf(accq0[reg]);
      Qb[rowbase + reg * 40 + 16 + m] = f2bf(accq1[reg]);
      Kb[rowbase + reg * 40 + m]      = f2bf(acck0[reg]);
      Kb[rowbase + reg * 40 + 16 + m] = f2bf(acck1[reg]);
    }
    bar_lds();  // LDS drained; W prefetches for next head stay in flight

    // Phase 2: A-frag rows 16w+m, k=r=q*8..+7; B-frags from Kb per n-tile.
    short8 qa = *(const short8*)&Qb[(16 * w + m) * 40 + q * 8];
    f32x4 acc[4];
#pragma unroll
    for (int nt = 0; nt < 4; ++nt) {
      short8 kb = *(const short8*)&Kb[(16 * nt + m) * 40 + q * 8];
      acc[nt] = __builtin_amdgcn_mfma_f32_16x16x32_bf16(
          qa, kb, f32x4{0.f, 0.f, 0.f, 0.f}, 0, 0, 0);
    }
#pragma unroll
    for (int reg = 0; reg < 4; ++reg) {
      float e = __expf(GAMMA * acc[0][reg]) + __expf(GAMMA * acc[1][reg]) +
                __expf(GAMMA * acc[2][reg]) + __expf(GAMMA * acc[3][reg]);
      e += __shfl_xor(e, 1, 64);
      e += __shfl_xor(e, 2, 64);
      e += __shfl_xor(e, 4, 64);
      e += __shfl_xor(e, 8, 64);
      part += (m == 0) ? __logf(e) : 0.f;  // one log per row 16w+4q+reg
    }
    bar_lds();  // all Qb/Kb reads done before next head's writes
  }
  float tot = block_sum_256(part, tmp);
  if (t == 0) atomicAdd(out + b, -tot * (1.0f / GAMMA));
}

// ---------------------------------------------------------------------------
// Fallback kernels (no-workspace tier).
// ---------------------------------------------------------------------------
__global__ __launch_bounds__(256) void k_xz(const float* __restrict__ x,
                                            const float* __restrict__ z,
                                            const float* __restrict__ vb,
                                            const float* __restrict__ eb,
                                            const float* __restrict__ pb,
                                            float* __restrict__ out) {
  __shared__ float tmp[4];
  int b = blockIdx.x, t = threadIdx.x;
  const float4* xb = (const float4*)(x + (size_t)b * 12288);
  const float4* vb4 = (const float4*)vb;
  float s = 0.f;
  for (int i = t; i < 3072; i += 256) {
    float4 xv = xb[i];
    float4 bv = vb4[i];
    s += 0.5f * dot4(xv, xv) - dot4(bv, xv);
  }
  const float4* zb = (const float4*)(z + (size_t)b * 16384);
  const float4* pb4 = (const float4*)pb;
  const float4* eb4 = (const float4*)eb;
  for (int i = t; i < 4096; i += 256) {
    float4 zv = zb[i];
    float4 pv = pb4[i];
    float4 ev = eb4[i & 63];
    float4 c;
    c.x = pv.x + ev.x; c.y = pv.y + ev.y; c.z = pv.z + ev.z; c.w = pv.w + ev.w;
    s += 0.5f * dot4(zv, zv) - dot4(zv, c);
  }
  float r = block_sum_256(s, tmp);
  if (t == 0) out[b] = r;
}

__global__ __launch_bounds__(256) void k_enc(const float* __restrict__ x,
                                             const float* __restrict__ z,
                                             const float* __restrict__ ew,
                                             float* __restrict__ out) {
  __shared__ float xs[12288];
  __shared__ float tmp[4];
  int b = blockIdx.x, t = threadIdx.x;
  const float4* xb4 = (const float4*)(x + (size_t)b * 12288);
  for (int i = t; i < 3072; i += 256) ((float4*)xs)[i] = xb4[i];
  __syncthreads();

  float acc[64];
#pragma unroll
  for (int p = 0; p < 64; ++p) acc[p] = 0.f;

  for (int k4 = 0; k4 < 48; ++k4) {
    float4 wv = *(const float4*)(ew + (size_t)t * 192 + k4 * 4);
    int c = k4 >> 4;
    int ii = (k4 >> 1) & 7;
    int jh = (k4 & 1) * 4;
    const float* base = xs + c * 4096 + ii * 64 + jh;
#pragma unroll
    for (int p = 0; p < 64; ++p) {
      float4 pv = *(const float4*)(base + (p >> 3) * 512 + (p & 7) * 8);
      acc[p] = fmaf(wv.x, pv.x,
               fmaf(wv.y, pv.y, fmaf(wv.z, pv.z, fmaf(wv.w, pv.w, acc[p]))));
    }
  }
  const float* zb = z + (size_t)b * 16384;
  float s = 0.f;
#pragma unroll
  for (int p = 0; p < 64; ++p) s += acc[p] * zb[p * 256 + t];
  float r = block_sum_256(s, tmp);
  if (t == 0) atomicAdd(out + b, -r);
}

__global__ __launch_bounds__(256) void k_mem(const float* __restrict__ z,
                                             const float* __restrict__ mw,
                                             float* __restrict__ out) {
  __shared__ float zs[16 * 256];
  __shared__ float tmp[4];
  int b = blockIdx.x >> 2, pt = blockIdx.x & 3, t = threadIdx.x;
  const float4* zb4 = (const float4*)(z + (size_t)b * 16384 + pt * 4096);
  for (int i = t; i < 1024; i += 256) ((float4*)zs)[i] = zb4[i];
  __syncthreads();

  const float4* m4 = (const float4*)mw;
  float4 acc[16];
#pragma unroll
  for (int pp = 0; pp < 16; ++pp) acc[pp] = make_float4(0.f, 0.f, 0.f, 0.f);

#pragma unroll 2
  for (int k4 = 0; k4 < 64; ++k4) {
    float4 w0 = m4[(4 * k4 + 0) * 256 + t];
    float4 w1 = m4[(4 * k4 + 1) * 256 + t];
    float4 w2 = m4[(4 * k4 + 2) * 256 + t];
    float4 w3 = m4[(4 * k4 + 3) * 256 + t];
#pragma unroll
    for (int pp = 0; pp < 16; ++pp) {
      float4 zv = *(const float4*)&zs[pp * 256 + k4 * 4];
      fma4(acc[pp], zv.x, w0);
      fma4(acc[pp], zv.y, w1);
      fma4(acc[pp], zv.z, w2);
      fma4(acc[pp], zv.w, w3);
    }
  }
  float total = 0.f;
#pragma unroll
  for (int pp = 0; pp < 16; ++pp) {
    float r;
    r = fmaxf(acc[pp].x, 0.f); total = fmaf(r, r, total);
    r = fmaxf(acc[pp].y, 0.f); total = fmaf(r, r, total);
    r = fmaxf(acc[pp].z, 0.f); total = fmaf(r, r, total);
    r = fmaxf(acc[pp].w, 0.f); total = fmaf(r, r, total);
  }
  float r = block_sum_256(total, tmp);
  if (t == 0) atomicAdd(out + b, -r);
}

__global__ __launch_bounds__(256) void k_attn(const float* __restrict__ z,
                                              const float* __restrict__ wq,
                                              const float* __restrict__ wk,
                                              float* __restrict__ out) {
  __shared__ float lds[8192];
  __shared__ float red[4];
  const int b = blockIdx.x >> 1, half = blockIdx.x & 1;
  const int t = threadIdx.x;
  const int lane = t & 63;
  const int w = __builtin_amdgcn_readfirstlane(t >> 6);
  const float4* zb4 = (const float4*)(z + (size_t)b * 16384);

  float qa[4][8], ka[4][8];
#pragma unroll
  for (int hh = 0; hh < 4; ++hh)
#pragma unroll
    for (int j = 0; j < 8; ++j) { qa[hh][j] = 0.f; ka[hh][j] = 0.f; }

  float4* lds4 = (float4*)lds;
  for (int dc = 0; dc < 2; ++dc) {
    __syncthreads();
    for (int i = t; i < 2048; i += 256) {
      int p = i >> 5, ld4 = i & 31;
      lds4[ld4 * 64 + (p ^ (ld4 & 7))] = zb4[p * 64 + dc * 32 + ld4];
    }
    __syncthreads();
#pragma unroll
    for (int hh = 0; hh < 4; ++hh) {
      int h = half * 4 + hh;
      const float* Wqb = wq + (size_t)h * 8192 + (size_t)(w * 8) * 256 + dc * 128;
      const float* Wkb = wk + (size_t)h * 8192 + (size_t)(w * 8) * 256 + dc * 128;
      for (int ld4 = 0; ld4 < 32; ++ld4) {
        float4 wv[8], kv[8];
#pragma unroll
        for (int j = 0; j < 8; ++j) {
          wv[j] = *(const float4*)(Wqb + j * 256 + ld4 * 4);
          kv[j] = *(const float4*)(Wkb + j * 256 + ld4 * 4);
        }
        float4 zv = lds4[ld4 * 64 + (lane ^ (ld4 & 7))];
#pragma unroll
        for (int j = 0; j < 8; ++j) {
          qa[hh][j] = fmaf(wv[j].x, zv.x, fmaf(wv[j].y, zv.y,
                      fmaf(wv[j].z, zv.z, fmaf(wv[j].w, zv.w, qa[hh][j]))));
          ka[hh][j] = fmaf(kv[j].x, zv.x, fmaf(kv[j].y, zv.y,
                      fmaf(kv[j].z, zv.z, fmaf(kv[j].w, zv.w, ka[hh][j]))));
        }
      }
    }
  }

  float* Qs = lds;
  float* Ks = lds + 2048;
  float lse = 0.f;
#pragma unroll
  for (int hh = 0; hh < 4; ++hh) {
    __syncthreads();
#pragma unroll
    for (int j = 0; j < 8; ++j) {
      Qs[(w * 8 + j) * 64 + lane] = qa[hh][j];
      Ks[(w * 8 + j) * 64 + lane] = ka[hh][j];
    }
    __syncthreads();
    float av[16];
#pragma unroll
    for (int mm = 0; mm < 16; ++mm) av[mm] = 0.f;
    for (int rr = 0; rr < 32; ++rr) {
      float kv = Ks[rr * 64 + lane];
      const float* qrow = &Qs[rr * 64 + w * 16];
      float4 q0 = *(const float4*)(qrow + 0);
      float4 q1 = *(const float4*)(qrow + 4);
      float4 q2 = *(const float4*)(qrow + 8);
      float4 q3 = *(const float4*)(qrow + 12);
      av[0]  = fmaf(q0.x, kv, av[0]);  av[1]  = fmaf(q0.y, kv, av[1]);
      av[2]  = fmaf(q0.z, kv, av[2]);  av[3]  = fmaf(q0.w, kv, av[3]);
      av[4]  = fmaf(q1.x, kv, av[4]);  av[5]  = fmaf(q1.y, kv, av[5]);
      av[6]  = fmaf(q1.z, kv, av[6]);  av[7]  = fmaf(q1.w, kv, av[7]);
      av[8]  = fmaf(q2.x, kv, av[8]);  av[9]  = fmaf(q2.y, kv, av[9]);
      av[10] = fmaf(q2.z, kv, av[10]); av[11] = fmaf(q2.w, kv, av[11]);
      av[12] = fmaf(q3.x, kv, av[12]); av[13] = fmaf(q3.w, kv, av[13]);
      av[14] = fmaf(q3.z, kv, av[14]); av[15] = fmaf(q3.w, kv, av[15]);
    }
#pragma unroll
    for (int mm = 0; mm < 16; ++mm) {
      float e = __expf(GAMMA * av[mm]);
#pragma unroll
      for (int off = 32; off; off >>= 1) e += __shfl_xor(e, off, 64);
      lse += __logf(e);
    }
  }
  if (lane == 0) red[w] = lse;
  __syncthreads();
  if (t == 0)
    atomicAdd(out + b, -(red[0] + red[1] + red[2] + red[3]) * (1.0f / GAMMA));
}

// ---------------------------------------------------------------------------
extern "C" void kernel_launch(void* const* d_in, const int* in_sizes, int n_in,
                              void* d_out, int out_size, void* d_ws,
                              size_t ws_size, hipStream_t stream) {
  (void)in_sizes; (void)n_in; (void)out_size;
  const float* x  = (const float*)d_in[0];
  const float* z  = (const float*)d_in[1];
  const float* ew = (const float*)d_in[2];
  const float* eb = (const float*)d_in[3];
  const float* vb = (const float*)d_in[4];
  const float* pb = (const float*)d_in[5];
  const float* mw = (const float*)d_in[6];
  const float* wq = (const float*)d_in[7];
  const float* wk = (const float*)d_in[8];
  float* out = (float*)d_out;

  const size_t Z_B  = (size_t)1024 * 64 * 256 * 2;  // 33.55 MB zb16
  const size_t MT_B = (size_t)1024 * 256 * 2;       // 0.52 MB mtf
  const size_t W_B  = (size_t)8 * 32 * 256 * 2;     // 128 KB each wqf/wkf
  const size_t EW_B = (size_t)96 * 64 * 8 * 2;      // 96 KB ewt
  const size_t FULL = Z_B + MT_B + 2 * W_B + EW_B;  // ~34.4 MB

  ushort* zb16 = (ushort*)d_ws;
  ushort* mtf  = (ushort*)((char*)d_ws + Z_B);
  ushort* wqf  = (ushort*)((char*)d_ws + Z_B + MT_B);
  ushort* wkf  = (ushort*)((char*)d_ws + Z_B + MT_B + W_B);
  ushort* ewt  = (ushort*)((char*)d_ws + Z_B + MT_B + 2 * W_B);

  if (ws_size >= FULL) {
    hipMemsetAsync(out, 0, 1024 * sizeof(float), stream);
    k_z_cvt2<<<2048, 256, 0, stream>>>(z, eb, pb, out, zb16);
    k_cvt_weights_v3<<<216, 256, 0, stream>>>(wq, wk, ew, mw,
                                              wqf, wkf, ewt, mtf);
    k_enc_v3 <<<1024, 256, 0, stream>>>(x, vb, ewt, zb16, out);
    k_mem_v5 <<<2048, 256, 0, stream>>>(zb16, mtf, out);
    k_attn_v5<<<2048, 256, 0, stream>>>(zb16, wqf, wkf, out);
  } else {
    k_xz  <<<1024, 256, 0, stream>>>(x, z, vb, eb, pb, out);
    k_enc <<<1024, 256, 0, stream>>>(x, z, ew, out);
    k_mem <<<4096, 256, 0, stream>>>(z, mw, out);
    k_attn<<<2048, 256, 0, stream>>>(z, wq, wk, out);
  }
}

// Round 4
// 253.885 us; speedup vs baseline: 1.7156x; 1.0287x over previous
//
#include <hip/hip_runtime.h>
#include <hip/hip_bf16.h>

#define GAMMA 0.25f

// Shapes: B=1024, C=3, H=64, D=256, NP=64 (8x8 grid of 8x8 patches),
//         M=1024, NH=8, R=32, P=8.  fp32 in/out.  out[b] = quad - coupling.
//
// R4: kill per-wave B-fragment duplication (R3 counters: attn_v5 56us at
// MfmaUtil 12.6% — 512KB/block of W re-loads at 1:1 MFMA:load).
//  - k_attn_v6: fused proj+lse. zf-staged GEMM (acc[4][4], 16 MFMA : 4
//    loads, per-wave-private columns of Wcat) -> f2bf -> LDS [p][r] tile
//    (union with zf) -> phase-2 QK^T+softmax entirely from LDS. No global
//    Q/K, no per-head barriers, same 34.4MB workspace.
//  - k_enc_v4: ewt is wave-SHARED -> stage 12KB ks-chunks in LDS (reg-staged
//    double buffer), 12 MFMA/chunk from ds_read.  4x less L2 traffic.

typedef __attribute__((ext_vector_type(8))) short short8;  // 8 bf16 (4 VGPRs)
typedef __attribute__((ext_vector_type(4))) float f32x4;   // 4 fp32 acc

__device__ __forceinline__ float dot4(float4 a, float4 b) {
  return fmaf(a.x, b.x, fmaf(a.y, b.y, fmaf(a.z, b.z, a.w * b.w)));
}

__device__ __forceinline__ void fma4(float4& a, float s, float4 w) {
  a.x = fmaf(s, w.x, a.x); a.y = fmaf(s, w.y, a.y);
  a.z = fmaf(s, w.z, a.z); a.w = fmaf(s, w.w, a.w);
}

__device__ __forceinline__ ushort f2bf(float f) {
  __hip_bfloat16 h = __float2bfloat16(f);  // RNE
  return *reinterpret_cast<ushort*>(&h);
}

__device__ __forceinline__ float bf2f(ushort u) {
  union { unsigned int i; float f; } v;
  v.i = ((unsigned int)u) << 16;
  return v.f;
}

// 256-thread block sum; result valid on all threads.
__device__ __forceinline__ float block_sum_256(float v, float* tmp) {
#pragma unroll
  for (int off = 32; off; off >>= 1) v += __shfl_down(v, off, 64);
  int w = threadIdx.x >> 6;
  if ((threadIdx.x & 63) == 0) tmp[w] = v;
  __syncthreads();
  return tmp[0] + tmp[1] + tmp[2] + tmp[3];
}

// ---------------------------------------------------------------------------
// Kernel 1: z pass, grid 2048.  quad_z - phi_bias - phi_pos, z -> bf16.
// ---------------------------------------------------------------------------
__global__ __launch_bounds__(256) void k_z_cvt2(const float* __restrict__ z,
                                                const float* __restrict__ eb,
                                                const float* __restrict__ pb,
                                                float* __restrict__ out,
                                                ushort* __restrict__ zb16) {
  __shared__ float tmp[4];
  int bid = blockIdx.x, b = bid >> 1, hz = bid & 1, t = threadIdx.x;
  const float4* zb = (const float4*)(z + (size_t)b * 16384);
  const float4* pb4 = (const float4*)pb;
  const float4* eb4 = (const float4*)eb;
  ushort4* z16o = (ushort4*)(zb16 + (size_t)b * 16384);
  float s = 0.f;
  const int i0 = hz * 2048;
  for (int i = i0 + t; i < i0 + 2048; i += 256) {
    float4 zv = zb[i];
    float4 pv = pb4[i];
    float4 ev = eb4[i & 63];
    float4 c;
    c.x = pv.x + ev.x; c.y = pv.y + ev.y; c.z = pv.z + ev.z; c.w = pv.w + ev.w;
    s += 0.5f * dot4(zv, zv) - dot4(zv, c);
    ushort4 o;
    o.x = f2bf(zv.x); o.y = f2bf(zv.y); o.z = f2bf(zv.z); o.w = f2bf(zv.w);
    z16o[i] = o;
  }
  float r = block_sum_256(s, tmp);
  if (t == 0) atomicAdd(out + b, r);
}

// ---------------------------------------------------------------------------
// Weight conversion, fragment-linear (one launch, block ranges):
// [0,64)   wcf: frag=ctg*8+kc (ctg 0..31): Wcat cols [h][qk][rr], 256 frags
//          B-frag elem: col = 16*ctg+(l&15) -> (h=col>>6, qk, rr=col&31),
//          k = kc*32+(l>>4)*8+j, src = (qk?wk:wq)[h][rr][k].
// [64,88)  ewt: frag=ks*12+ct: B[d][kcol]=ew[d*192+kcol]   96 frags
// [88,216) mtf: frag=C*8+kc:   B[k][m]=mw[k][C*16+m]      512 frags
// Each fragment = contiguous [l][8] 1KB wave-block.
// ---------------------------------------------------------------------------
__global__ __launch_bounds__(256) void k_cvt_weights_v4(
    const float* __restrict__ wq, const float* __restrict__ wk,
    const float* __restrict__ ew, const float* __restrict__ mw,
    ushort* __restrict__ wcf, ushort* __restrict__ ewt,
    ushort* __restrict__ mtf) {
  int bid = blockIdx.x, t = threadIdx.x;
  ushort o[8];
  if (bid < 64) {
    int tid = bid * 256 + t;  // 0..16383
    int frag = tid >> 6, l = tid & 63;
    int ctg = frag >> 3, kc = frag & 7;
    int col = ctg * 16 + (l & 15);
    int h = col >> 6, qk = (col >> 5) & 1, rr = col & 31;
    int k0 = kc * 32 + (l >> 4) * 8;
    const float* s = (qk ? wk : wq) + ((size_t)h * 32 + rr) * 256 + k0;
#pragma unroll
    for (int i = 0; i < 8; ++i) o[i] = f2bf(s[i]);
    *(ushort4*)(wcf + (size_t)tid * 8) = *(ushort4*)&o[0];
    *(ushort4*)(wcf + (size_t)tid * 8 + 4) = *(ushort4*)&o[4];
  } else if (bid < 88) {
    int tid = (bid - 64) * 256 + t;  // 0..6143
    int frag = tid >> 6, l = tid & 63;
    int ks = frag / 12, ct = frag % 12;
    const float* s = ew + (size_t)(ks * 32 + (l >> 4) * 8) * 192 +
                     ct * 16 + (l & 15);
#pragma unroll
    for (int i = 0; i < 8; ++i) o[i] = f2bf(s[(size_t)i * 192]);
    *(ushort4*)(ewt + (size_t)tid * 8) = *(ushort4*)&o[0];
    *(ushort4*)(ewt + (size_t)tid * 8 + 4) = *(ushort4*)&o[4];
  } else {
    int tid = (bid - 88) * 256 + t;  // 0..32767
    int frag = tid >> 6, l = tid & 63;
    int C = frag >> 3, kc = frag & 7;
    int k0 = kc * 32 + (l >> 4) * 8, col = C * 16 + (l & 15);
#pragma unroll
    for (int i = 0; i < 8; ++i) o[i] = f2bf(mw[(size_t)(k0 + i) * 1024 + col]);
    *(ushort4*)(mtf + (size_t)tid * 8) = *(ushort4*)&o[0];
    *(ushort4*)(mtf + (size_t)tid * 8 + 4) = *(ushort4*)&o[4];
  }
}

// ---------------------------------------------------------------------------
// Kernel 2: quad_x - phi_vis - phi_enc.  Y = z·W (64x192), dotted with
// xpatch from LDS.  ewt is wave-SHARED: stage 12KB ks-chunks into a
// double-buffered LDS region (reg-staged: global->reg early, reg->LDS after
// the barrier), 12 MFMA per chunk via ds_read_b128.
// ---------------------------------------------------------------------------
__global__ __launch_bounds__(256) void k_enc_v4(
    const float* __restrict__ x, const float* __restrict__ vb,
    const ushort* __restrict__ ewt, const ushort* __restrict__ zb16,
    float* __restrict__ out) {
  __shared__ ushort xs[12288];      // 24 KB: x[b] bf16, NCHW layout
  __shared__ ushort ebuf[2][6144];  // 2 x 12 KB: ewt ks-chunk double buffer
  __shared__ float tmp[4];
  const int b = blockIdx.x, t = threadIdx.x, l = t & 63, w = t >> 6;
  const int q = l >> 4, m = l & 15;

  // z A-frags (global, issued first so they overlap the x staging).
  const ushort* Az = zb16 + ((size_t)b * 64 + 16 * w + m) * 256 + q * 8;
  short8 a[8];
#pragma unroll
  for (int ks = 0; ks < 8; ++ks) a[ks] = *(const short8*)(Az + ks * 32);

  // chunk-0 staging loads (in flight during x staging)
  short8 st[3];
#pragma unroll
  for (int i = 0; i < 3; ++i)
    st[i] = *(const short8*)(ewt + (size_t)(t + i * 256) * 8);

  // Stage x -> bf16 LDS; accumulate quad_x - phi_vis.
  const float4* xb = (const float4*)(x + (size_t)b * 12288);
  const float4* vb4 = (const float4*)vb;
  ushort4* xs4 = (ushort4*)xs;
  float s = 0.f;
  for (int i = t; i < 3072; i += 256) {
    float4 xv = xb[i];
    float4 bv = vb4[i];
    s += 0.5f * dot4(xv, xv) - dot4(bv, xv);
    ushort4 o;
    o.x = f2bf(xv.x); o.y = f2bf(xv.y); o.z = f2bf(xv.z); o.w = f2bf(xv.w);
    xs4[i] = o;
  }
#pragma unroll
  for (int i = 0; i < 3; ++i)
    *(short8*)(ebuf[0] + (size_t)(t + i * 256) * 8) = st[i];
  __syncthreads();

  f32x4 acc[12];
#pragma unroll
  for (int ct = 0; ct < 12; ++ct) acc[ct] = f32x4{0.f, 0.f, 0.f, 0.f};

#pragma unroll
  for (int ks = 0; ks < 8; ++ks) {
    const int cur = ks & 1;
    if (ks < 7) {
#pragma unroll
      for (int i = 0; i < 3; ++i)
        st[i] = *(const short8*)(ewt + (size_t)(ks + 1) * 6144 +
                                 (size_t)(t + i * 256) * 8);
    }
#pragma unroll
    for (int ct = 0; ct < 12; ++ct) {
      short8 bv = *(const short8*)(ebuf[cur] + (size_t)(ct * 64 + l) * 8);
      acc[ct] = __builtin_amdgcn_mfma_f32_16x16x32_bf16(a[ks], bv, acc[ct], 0, 0, 0);
    }
    if (ks < 7) {
#pragma unroll
      for (int i = 0; i < 3; ++i)
        *(short8*)(ebuf[cur ^ 1] + (size_t)(t + i * 256) * 8) = st[i];
    }
    __syncthreads();
  }

  // Epilogue: D element (row p=16w+4q+reg, col k=16ct+m) * x[p,k] from LDS.
#pragma unroll
  for (int ct = 0; ct < 12; ++ct) {
#pragma unroll
    for (int reg = 0; reg < 4; ++reg) {
      const int p = 16 * w + 4 * q + reg, gi = p >> 3, gj = p & 7;
      const int k = ct * 16 + m, c = k >> 6, r2 = k & 63;
      const int ii = r2 >> 3, jj = r2 & 7;
      s -= acc[ct][reg] * bf2f(xs[c * 4096 + (gi * 8 + ii) * 64 + gj * 8 + jj]);
    }
  }
  float r = block_sum_256(s, tmp);
  if (t == 0) atomicAdd(out + b, r);  // += quad_x - phi_vis - phi_enc
}

// ---------------------------------------------------------------------------
// Kernel 3: phi_mem.  Grid 2048: block = (b, ct-pair).  (unchanged R3)
// ---------------------------------------------------------------------------
__global__ __launch_bounds__(256) void k_mem_v5(const ushort* __restrict__ zb,
                                                const ushort* __restrict__ mtf,
                                                float* __restrict__ out) {
  __shared__ ushort zf[2048 * 8];  // 32 KB: z[b] fragment-ordered [w2][ks][l]
  __shared__ float tmp[4];
  const int t = threadIdx.x, l = t & 63, w = t >> 6;
  const int b = blockIdx.x >> 1, cth = blockIdx.x & 1;

#pragma unroll
  for (int j = 0; j < 8; ++j) {
    int i = t + j * 256;
    int l2 = i & 63, ks = (i >> 6) & 7, w2 = i >> 9;
    short8 v = *(const short8*)(zb + ((size_t)b * 64 + 16 * w2 + (l2 & 15)) * 256
                                + ks * 32 + (l2 >> 4) * 8);
    *(short8*)(zf + (size_t)i * 8) = v;
  }
  __syncthreads();

  float s = 0.f;
#pragma unroll 1
  for (int ctl = 0; ctl < 2; ++ctl) {
    const int ct = cth * 2 + ctl;
    const ushort* Bb = mtf + ((size_t)(ct * 16 + w * 4) * 8) * 512 + (size_t)l * 8;
    short8 fb[2][4];
#pragma unroll
    for (int c = 0; c < 4; ++c) fb[0][c] = *(const short8*)(Bb + (c * 8 + 0) * 512);
#pragma unroll
    for (int c = 0; c < 4; ++c) fb[1][c] = *(const short8*)(Bb + (c * 8 + 1) * 512);

    f32x4 acc[4][4];
#pragma unroll
    for (int r = 0; r < 4; ++r)
#pragma unroll
      for (int c = 0; c < 4; ++c) acc[r][c] = f32x4{0.f, 0.f, 0.f, 0.f};

#pragma unroll
    for (int kc = 0; kc < 8; ++kc) {
      const int cur = kc & 1;
      short8 a4[4];
#pragma unroll
      for (int r = 0; r < 4; ++r)
        a4[r] = *(const short8*)(zf + (size_t)((r * 8 + kc) * 64 + l) * 8);
#pragma unroll
      for (int r = 0; r < 4; ++r)
#pragma unroll
        for (int c = 0; c < 4; ++c)
          acc[r][c] = __builtin_amdgcn_mfma_f32_16x16x32_bf16(a4[r], fb[cur][c],
                                                              acc[r][c], 0, 0, 0);
      if (kc < 6) {
#pragma unroll
        for (int c = 0; c < 4; ++c)
          fb[cur][c] = *(const short8*)(Bb + (c * 8 + kc + 2) * 512);
      }
    }
#pragma unroll
    for (int r = 0; r < 4; ++r)
#pragma unroll
      for (int c = 0; c < 4; ++c)
#pragma unroll
        for (int e = 0; e < 4; ++e) {
          float rr = fmaxf(acc[r][c][e], 0.f);
          s = fmaf(rr, rr, s);
        }
  }
  float r = block_sum_256(s, tmp);
  if (t == 0) atomicAdd(out + b, -r);
}

// ---------------------------------------------------------------------------
// Kernel 4: phi_att fused (proj GEMM + lse).  Grid 2048 = (b, half).
// Phase A: zf-staged GEMM z(64x256)·Wcat_half^T(256x256): wave w owns col
//   groups ctg = half*16+w*4+c, acc[4][4], 16 MFMA : 4 B-loads (private, no
//   duplication), depth-2 prefetch.  Phase B: f2bf -> dstg[p][r] (stride
//   264, unioned with zf), barrier.  Phase C: per head QK^T from LDS +
//   softmax; no global loads, no per-head barriers.
// ---------------------------------------------------------------------------
__global__ __launch_bounds__(256) void k_attn_v6(
    const ushort* __restrict__ zb, const ushort* __restrict__ wcf,
    float* __restrict__ out) {
  __shared__ ushort ubuf[64 * 264];  // 33.8 KB: zf (first 16K) then dstg
  __shared__ float tmp[4];
  const int t = threadIdx.x, l = t & 63, w = t >> 6;
  const int b = blockIdx.x >> 1, half = blockIdx.x & 1;
  const int q = l >> 4, m = l & 15;

  // Stage zf: z[b] fragment-ordered (same as k_mem_v5).
#pragma unroll
  for (int j = 0; j < 8; ++j) {
    int i = t + j * 256;
    int l2 = i & 63, ks = (i >> 6) & 7, w2 = i >> 9;
    short8 v = *(const short8*)(zb + ((size_t)b * 64 + 16 * w2 + (l2 & 15)) * 256
                                + ks * 32 + (l2 >> 4) * 8);
    *(short8*)(ubuf + (size_t)i * 8) = v;
  }
  __syncthreads();

  // Phase A: proj GEMM.
  const ushort* Bb = wcf + ((size_t)((half * 16 + w * 4) * 8)) * 512 +
                     (size_t)l * 8;
  short8 fb[2][4];
#pragma unroll
  for (int c = 0; c < 4; ++c) fb[0][c] = *(const short8*)(Bb + (c * 8 + 0) * 512);
#pragma unroll
  for (int c = 0; c < 4; ++c) fb[1][c] = *(const short8*)(Bb + (c * 8 + 1) * 512);

  f32x4 acc[4][4];
#pragma unroll
  for (int r = 0; r < 4; ++r)
#pragma unroll
    for (int c = 0; c < 4; ++c) acc[r][c] = f32x4{0.f, 0.f, 0.f, 0.f};

#pragma unroll
  for (int kc = 0; kc < 8; ++kc) {
    const int cur = kc & 1;
    short8 a4[4];
#pragma unroll
    for (int r = 0; r < 4; ++r)
      a4[r] = *(const short8*)(ubuf + (size_t)((r * 8 + kc) * 64 + l) * 8);
#pragma unroll
    for (int r = 0; r < 4; ++r)
#pragma unroll
      for (int c = 0; c < 4; ++c)
        acc[r][c] = __builtin_amdgcn_mfma_f32_16x16x32_bf16(a4[r], fb[cur][c],
                                                            acc[r][c], 0, 0, 0);
    if (kc < 6) {
#pragma unroll
      for (int c = 0; c < 4; ++c)
        fb[cur][c] = *(const short8*)(Bb + (c * 8 + kc + 2) * 512);
    }
  }
  __syncthreads();  // all zf reads done; ubuf becomes dstg

  // Phase B: D (row p = 16rt+4q+reg, col r_half = (4w+c)*16+m) -> dstg.
  ushort* dstg = ubuf;
#pragma unroll
  for (int rt = 0; rt < 4; ++rt)
#pragma unroll
    for (int c = 0; c < 4; ++c)
#pragma unroll
      for (int reg = 0; reg < 4; ++reg)
        dstg[(size_t)(16 * rt + 4 * q + reg) * 264 + (4 * w + c) * 16 + m] =
            f2bf(acc[rt][c][reg]);
  __syncthreads();

  // Phase C: per head hh: Q rows 16w.., K all tiles; r_half = hh*64 (+32 K).
  float part = 0.f;
#pragma unroll
  for (int hh = 0; hh < 4; ++hh) {
    short8 qa = *(const short8*)(dstg + (size_t)(16 * w + m) * 264 +
                                 hh * 64 + q * 8);
    f32x4 a2[4];
#pragma unroll
    for (int nt = 0; nt < 4; ++nt) {
      short8 kb = *(const short8*)(dstg + (size_t)(16 * nt + m) * 264 +
                                   hh * 64 + 32 + q * 8);
      a2[nt] = __builtin_amdgcn_mfma_f32_16x16x32_bf16(
          qa, kb, f32x4{0.f, 0.f, 0.f, 0.f}, 0, 0, 0);
    }
#pragma unroll
    for (int reg = 0; reg < 4; ++reg) {
      float e = __expf(GAMMA * a2[0][reg]) + __expf(GAMMA * a2[1][reg]) +
                __expf(GAMMA * a2[2][reg]) + __expf(GAMMA * a2[3][reg]);
      e += __shfl_xor(e, 1, 64);
      e += __shfl_xor(e, 2, 64);
      e += __shfl_xor(e, 4, 64);
      e += __shfl_xor(e, 8, 64);
      part += (m == 0) ? __logf(e) : 0.f;  // one log per row 16w+4q+reg
    }
  }
  float tot = block_sum_256(part, tmp);
  if (t == 0) atomicAdd(out + b, -tot * (1.0f / GAMMA));
}

// ---------------------------------------------------------------------------
// Fallback kernels (no-workspace tier).
// ---------------------------------------------------------------------------
__global__ __launch_bounds__(256) void k_xz(const float* __restrict__ x,
                                            const float* __restrict__ z,
                                            const float* __restrict__ vb,
                                            const float* __restrict__ eb,
                                            const float* __restrict__ pb,
                                            float* __restrict__ out) {
  __shared__ float tmp[4];
  int b = blockIdx.x, t = threadIdx.x;
  const float4* xb = (const float4*)(x + (size_t)b * 12288);
  const float4* vb4 = (const float4*)vb;
  float s = 0.f;
  for (int i = t; i < 3072; i += 256) {
    float4 xv = xb[i];
    float4 bv = vb4[i];
    s += 0.5f * dot4(xv, xv) - dot4(bv, xv);
  }
  const float4* zb = (const float4*)(z + (size_t)b * 16384);
  const float4* pb4 = (const float4*)pb;
  const float4* eb4 = (const float4*)eb;
  for (int i = t; i < 4096; i += 256) {
    float4 zv = zb[i];
    float4 pv = pb4[i];
    float4 ev = eb4[i & 63];
    float4 c;
    c.x = pv.x + ev.x; c.y = pv.y + ev.y; c.z = pv.z + ev.z; c.w = pv.w + ev.w;
    s += 0.5f * dot4(zv, zv) - dot4(zv, c);
  }
  float r = block_sum_256(s, tmp);
  if (t == 0) out[b] = r;
}

__global__ __launch_bounds__(256) void k_enc(const float* __restrict__ x,
                                             const float* __restrict__ z,
                                             const float* __restrict__ ew,
                                             float* __restrict__ out) {
  __shared__ float xs[12288];
  __shared__ float tmp[4];
  int b = blockIdx.x, t = threadIdx.x;
  const float4* xb4 = (const float4*)(x + (size_t)b * 12288);
  for (int i = t; i < 3072; i += 256) ((float4*)xs)[i] = xb4[i];
  __syncthreads();

  float acc[64];
#pragma unroll
  for (int p = 0; p < 64; ++p) acc[p] = 0.f;

  for (int k4 = 0; k4 < 48; ++k4) {
    float4 wv = *(const float4*)(ew + (size_t)t * 192 + k4 * 4);
    int c = k4 >> 4;
    int ii = (k4 >> 1) & 7;
    int jh = (k4 & 1) * 4;
    const float* base = xs + c * 4096 + ii * 64 + jh;
#pragma unroll
    for (int p = 0; p < 64; ++p) {
      float4 pv = *(const float4*)(base + (p >> 3) * 512 + (p & 7) * 8);
      acc[p] = fmaf(wv.x, pv.x,
               fmaf(wv.y, pv.y, fmaf(wv.z, pv.z, fmaf(wv.w, pv.w, acc[p]))));
    }
  }
  const float* zb = z + (size_t)b * 16384;
  float s = 0.f;
#pragma unroll
  for (int p = 0; p < 64; ++p) s += acc[p] * zb[p * 256 + t];
  float r = block_sum_256(s, tmp);
  if (t == 0) atomicAdd(out + b, -r);
}

__global__ __launch_bounds__(256) void k_mem(const float* __restrict__ z,
                                             const float* __restrict__ mw,
                                             float* __restrict__ out) {
  __shared__ float zs[16 * 256];
  __shared__ float tmp[4];
  int b = blockIdx.x >> 2, pt = blockIdx.x & 3, t = threadIdx.x;
  const float4* zb4 = (const float4*)(z + (size_t)b * 16384 + pt * 4096);
  for (int i = t; i < 1024; i += 256) ((float4*)zs)[i] = zb4[i];
  __syncthreads();

  const float4* m4 = (const float4*)mw;
  float4 acc[16];
#pragma unroll
  for (int pp = 0; pp < 16; ++pp) acc[pp] = make_float4(0.f, 0.f, 0.f, 0.f);

#pragma unroll 2
  for (int k4 = 0; k4 < 64; ++k4) {
    float4 w0 = m4[(4 * k4 + 0) * 256 + t];
    float4 w1 = m4[(4 * k4 + 1) * 256 + t];
    float4 w2 = m4[(4 * k4 + 2) * 256 + t];
    float4 w3 = m4[(4 * k4 + 3) * 256 + t];
#pragma unroll
    for (int pp = 0; pp < 16; ++pp) {
      float4 zv = *(const float4*)&zs[pp * 256 + k4 * 4];
      fma4(acc[pp], zv.x, w0);
      fma4(acc[pp], zv.y, w1);
      fma4(acc[pp], zv.z, w2);
      fma4(acc[pp], zv.w, w3);
    }
  }
  float total = 0.f;
#pragma unroll
  for (int pp = 0; pp < 16; ++pp) {
    float r;
    r = fmaxf(acc[pp].x, 0.f); total = fmaf(r, r, total);
    r = fmaxf(acc[pp].y, 0.f); total = fmaf(r, r, total);
    r = fmaxf(acc[pp].z, 0.f); total = fmaf(r, r, total);
    r = fmaxf(acc[pp].w, 0.f); total = fmaf(r, r, total);
  }
  float r = block_sum_256(total, tmp);
  if (t == 0) atomicAdd(out + b, -r);
}

__global__ __launch_bounds__(256) void k_attn(const float* __restrict__ z,
                                              const float* __restrict__ wq,
                                              const float* __restrict__ wk,
                                              float* __restrict__ out) {
  __shared__ float lds[8192];
  __shared__ float red[4];
  const int b = blockIdx.x >> 1, half = blockIdx.x & 1;
  const int t = threadIdx.x;
  const int lane = t & 63;
  const int w = __builtin_amdgcn_readfirstlane(t >> 6);
  const float4* zb4 = (const float4*)(z + (size_t)b * 16384);

  float qa[4][8], ka[4][8];
#pragma unroll
  for (int hh = 0; hh < 4; ++hh)
#pragma unroll
    for (int j = 0; j < 8; ++j) { qa[hh][j] = 0.f; ka[hh][j] = 0.f; }

  float4* lds4 = (float4*)lds;
  for (int dc = 0; dc < 2; ++dc) {
    __syncthreads();
    for (int i = t; i < 2048; i += 256) {
      int p = i >> 5, ld4 = i & 31;
      lds4[ld4 * 64 + (p ^ (ld4 & 7))] = zb4[p * 64 + dc * 32 + ld4];
    }
    __syncthreads();
#pragma unroll
    for (int hh = 0; hh < 4; ++hh) {
      int h = half * 4 + hh;
      const float* Wqb = wq + (size_t)h * 8192 + (size_t)(w * 8) * 256 + dc * 128;
      const float* Wkb = wk + (size_t)h * 8192 + (size_t)(w * 8) * 256 + dc * 128;
      for (int ld4 = 0; ld4 < 32; ++ld4) {
        float4 wv[8], kv[8];
#pragma unroll
        for (int j = 0; j < 8; ++j) {
          wv[j] = *(const float4*)(Wqb + j * 256 + ld4 * 4);
          kv[j] = *(const float4*)(Wkb + j * 256 + ld4 * 4);
        }
        float4 zv = lds4[ld4 * 64 + (lane ^ (ld4 & 7))];
#pragma unroll
        for (int j = 0; j < 8; ++j) {
          qa[hh][j] = fmaf(wv[j].x, zv.x, fmaf(wv[j].y, zv.y,
                      fmaf(wv[j].z, zv.z, fmaf(wv[j].w, zv.w, qa[hh][j]))));
          ka[hh][j] = fmaf(kv[j].x, zv.x, fmaf(kv[j].y, zv.y,
                      fmaf(kv[j].z, zv.z, fmaf(kv[j].w, zv.w, ka[hh][j]))));
        }
      }
    }
  }

  float* Qs = lds;
  float* Ks = lds + 2048;
  float lse = 0.f;
#pragma unroll
  for (int hh = 0; hh < 4; ++hh) {
    __syncthreads();
#pragma unroll
    for (int j = 0; j < 8; ++j) {
      Qs[(w * 8 + j) * 64 + lane] = qa[hh][j];
      Ks[(w * 8 + j) * 64 + lane] = ka[hh][j];
    }
    __syncthreads();
    float av[16];
#pragma unroll
    for (int mm = 0; mm < 16; ++mm) av[mm] = 0.f;
    for (int rr = 0; rr < 32; ++rr) {
      float kv = Ks[rr * 64 + lane];
      const float* qrow = &Qs[rr * 64 + w * 16];
      float4 q0 = *(const float4*)(qrow + 0);
      float4 q1 = *(const float4*)(qrow + 4);
      float4 q2 = *(const float4*)(qrow + 8);
      float4 q3 = *(const float4*)(qrow + 12);
      av[0]  = fmaf(q0.x, kv, av[0]);  av[1]  = fmaf(q0.y, kv, av[1]);
      av[2]  = fmaf(q0.z, kv, av[2]);  av[3]  = fmaf(q0.w, kv, av[3]);
      av[4]  = fmaf(q1.x, kv, av[4]);  av[5]  = fmaf(q1.y, kv, av[5]);
      av[6]  = fmaf(q1.z, kv, av[6]);  av[7]  = fmaf(q1.w, kv, av[7]);
      av[8]  = fmaf(q2.x, kv, av[8]);  av[9]  = fmaf(q2.y, kv, av[9]);
      av[10] = fmaf(q2.z, kv, av[10]); av[11] = fmaf(q2.w, kv, av[11]);
      av[12] = fmaf(q3.x, kv, av[12]); av[13] = fmaf(q3.y, kv, av[13]);
      av[14] = fmaf(q3.z, kv, av[14]); av[15] = fmaf(q3.w, kv, av[15]);
    }
#pragma unroll
    for (int mm = 0; mm < 16; ++mm) {
      float e = __expf(GAMMA * av[mm]);
#pragma unroll
      for (int off = 32; off; off >>= 1) e += __shfl_xor(e, off, 64);
      lse += __logf(e);
    }
  }
  if (lane == 0) red[w] = lse;
  __syncthreads();
  if (t == 0)
    atomicAdd(out + b, -(red[0] + red[1] + red[2] + red[3]) * (1.0f / GAMMA));
}

// ---------------------------------------------------------------------------
extern "C" void kernel_launch(void* const* d_in, const int* in_sizes, int n_in,
                              void* d_out, int out_size, void* d_ws,
                              size_t ws_size, hipStream_t stream) {
  (void)in_sizes; (void)n_in; (void)out_size;
  const float* x  = (const float*)d_in[0];
  const float* z  = (const float*)d_in[1];
  const float* ew = (const float*)d_in[2];
  const float* eb = (const float*)d_in[3];
  const float* vb = (const float*)d_in[4];
  const float* pb = (const float*)d_in[5];
  const float* mw = (const float*)d_in[6];
  const float* wq = (const float*)d_in[7];
  const float* wk = (const float*)d_in[8];
  float* out = (float*)d_out;

  const size_t Z_B  = (size_t)1024 * 64 * 256 * 2;  // 33.55 MB zb16
  const size_t MT_B = (size_t)1024 * 256 * 2;       // 0.52 MB mtf
  const size_t EW_B = (size_t)96 * 64 * 8 * 2;      // 96 KB ewt
  const size_t WC_B = (size_t)512 * 256 * 2;        // 256 KB wcf
  const size_t FULL = Z_B + MT_B + EW_B + WC_B;     // ~34.4 MB

  ushort* zb16 = (ushort*)d_ws;
  ushort* mtf  = (ushort*)((char*)d_ws + Z_B);
  ushort* ewt  = (ushort*)((char*)d_ws + Z_B + MT_B);
  ushort* wcf  = (ushort*)((char*)d_ws + Z_B + MT_B + EW_B);

  if (ws_size >= FULL) {
    hipMemsetAsync(out, 0, 1024 * sizeof(float), stream);
    k_z_cvt2<<<2048, 256, 0, stream>>>(z, eb, pb, out, zb16);
    k_cvt_weights_v4<<<216, 256, 0, stream>>>(wq, wk, ew, mw, wcf, ewt, mtf);
    k_enc_v4 <<<1024, 256, 0, stream>>>(x, vb, ewt, zb16, out);
    k_mem_v5 <<<2048, 256, 0, stream>>>(zb16, mtf, out);
    k_attn_v6<<<2048, 256, 0, stream>>>(zb16, wcf, out);
  } else {
    k_xz  <<<1024, 256, 0, stream>>>(x, z, vb, eb, pb, out);
    k_enc <<<1024, 256, 0, stream>>>(x, z, ew, out);
    k_mem <<<4096, 256, 0, stream>>>(z, mw, out);
    k_attn<<<2048, 256, 0, stream>>>(z, wq, wk, out);
  }
}

// Round 5
// 222.373 us; speedup vs baseline: 1.9587x; 1.1417x over previous
//
#include <hip/hip_runtime.h>
#include <hip/hip_bf16.h>

#define GAMMA 0.25f

// Shapes: B=1024, C=3, H=64, D=256, NP=64 (8x8 grid of 8x8 patches),
//         M=1024, NH=8, R=32, P=8.  fp32 in/out.  out[b] = quad - coupling.
//
// R5: mega-kernel. zb16 intermediate DELETED.  k_mega (one block per b,
// 64KB LDS, 2 blocks/CU): phase0 z fp32 -> quad_z terms + zf LDS tile
// (frag-ordered bf16); phase1 = mem (4 ct, mem_v5 body); phase2 = attn
// (2 halves, attn_v6 bodies; dstg = separate XOR-swizzled [64][256] tile,
// byte ^= (row&7)<<4).  One plain out[b] store.  k_enc_v5: enc_v4 with
// A-frags converted from z fp32 directly (L3-warm), atomicAdd.

typedef __attribute__((ext_vector_type(8))) short short8;  // 8 bf16 (4 VGPRs)
typedef __attribute__((ext_vector_type(4))) float f32x4;   // 4 fp32 acc

__device__ __forceinline__ float dot4(float4 a, float4 b) {
  return fmaf(a.x, b.x, fmaf(a.y, b.y, fmaf(a.z, b.z, a.w * b.w)));
}

__device__ __forceinline__ void fma4(float4& a, float s, float4 w) {
  a.x = fmaf(s, w.x, a.x); a.y = fmaf(s, w.y, a.y);
  a.z = fmaf(s, w.z, a.z); a.w = fmaf(s, w.w, a.w);
}

__device__ __forceinline__ ushort f2bf(float f) {
  __hip_bfloat16 h = __float2bfloat16(f);  // RNE
  return *reinterpret_cast<ushort*>(&h);
}

__device__ __forceinline__ float bf2f(ushort u) {
  union { unsigned int i; float f; } v;
  v.i = ((unsigned int)u) << 16;
  return v.f;
}

// 256-thread block sum; result valid on all threads.
__device__ __forceinline__ float block_sum_256(float v, float* tmp) {
#pragma unroll
  for (int off = 32; off; off >>= 1) v += __shfl_down(v, off, 64);
  int w = threadIdx.x >> 6;
  if ((threadIdx.x & 63) == 0) tmp[w] = v;
  __syncthreads();
  return tmp[0] + tmp[1] + tmp[2] + tmp[3];
}

// ---------------------------------------------------------------------------
// Weight conversion, fragment-linear (one launch, block ranges):
// [0,64)   wcf: frag=ctg*8+kc (ctg 0..31): Wcat cols [h][qk][rr], 256 frags
// [64,88)  ewt: frag=ks*12+ct: B[d][kcol]=ew[d*192+kcol]   96 frags
// [88,216) mtf: frag=C*8+kc:   B[k][m]=mw[k][C*16+m]      512 frags
// Each fragment = contiguous [l][8] 1KB wave-block.
// ---------------------------------------------------------------------------
__global__ __launch_bounds__(256) void k_cvt_weights_v4(
    const float* __restrict__ wq, const float* __restrict__ wk,
    const float* __restrict__ ew, const float* __restrict__ mw,
    ushort* __restrict__ wcf, ushort* __restrict__ ewt,
    ushort* __restrict__ mtf) {
  int bid = blockIdx.x, t = threadIdx.x;
  ushort o[8];
  if (bid < 64) {
    int tid = bid * 256 + t;  // 0..16383
    int frag = tid >> 6, l = tid & 63;
    int ctg = frag >> 3, kc = frag & 7;
    int col = ctg * 16 + (l & 15);
    int h = col >> 6, qk = (col >> 5) & 1, rr = col & 31;
    int k0 = kc * 32 + (l >> 4) * 8;
    const float* s = (qk ? wk : wq) + ((size_t)h * 32 + rr) * 256 + k0;
#pragma unroll
    for (int i = 0; i < 8; ++i) o[i] = f2bf(s[i]);
    *(ushort4*)(wcf + (size_t)tid * 8) = *(ushort4*)&o[0];
    *(ushort4*)(wcf + (size_t)tid * 8 + 4) = *(ushort4*)&o[4];
  } else if (bid < 88) {
    int tid = (bid - 64) * 256 + t;  // 0..6143
    int frag = tid >> 6, l = tid & 63;
    int ks = frag / 12, ct = frag % 12;
    const float* s = ew + (size_t)(ks * 32 + (l >> 4) * 8) * 192 +
                     ct * 16 + (l & 15);
#pragma unroll
    for (int i = 0; i < 8; ++i) o[i] = f2bf(s[(size_t)i * 192]);
    *(ushort4*)(ewt + (size_t)tid * 8) = *(ushort4*)&o[0];
    *(ushort4*)(ewt + (size_t)tid * 8 + 4) = *(ushort4*)&o[4];
  } else {
    int tid = (bid - 88) * 256 + t;  // 0..32767
    int frag = tid >> 6, l = tid & 63;
    int C = frag >> 3, kc = frag & 7;
    int k0 = kc * 32 + (l >> 4) * 8, col = C * 16 + (l & 15);
#pragma unroll
    for (int i = 0; i < 8; ++i) o[i] = f2bf(mw[(size_t)(k0 + i) * 1024 + col]);
    *(ushort4*)(mtf + (size_t)tid * 8) = *(ushort4*)&o[0];
    *(ushort4*)(mtf + (size_t)tid * 8 + 4) = *(ushort4*)&o[4];
  }
}

// ---------------------------------------------------------------------------
// Mega-kernel: quad_z - phi_bias - phi_pos - phi_mem - phi_att, per b.
// LDS: SL[0,16384) = zf (frag-ordered z[b] bf16), SL[16384,32768) = dstg
// (XOR-swizzled [64][256] Q|K tile per half).  64 KB -> 2 blocks/CU.
// ---------------------------------------------------------------------------
__global__ __launch_bounds__(256) void k_mega(
    const float* __restrict__ z, const float* __restrict__ eb,
    const float* __restrict__ pb, const ushort* __restrict__ mtf,
    const ushort* __restrict__ wcf, float* __restrict__ out) {
  __shared__ ushort SL[32768];  // 64 KB
  const int t = threadIdx.x, l = t & 63, w = t >> 6;
  const int b = blockIdx.x;
  const int q = l >> 4, m = l & 15;
  float s = 0.f;

  // ---- Phase 0: z fp32 -> quad_z - phi_bias - phi_pos; zf (bf16) to LDS.
  // i = t + n*256: p = i>>6 constant per wave -> z reads fully coalesced.
  {
    const float4* zb4 = (const float4*)(z + (size_t)b * 16384);
    const float4* pb4 = (const float4*)pb;
    const float4* eb4 = (const float4*)eb;
#pragma unroll
    for (int n = 0; n < 16; ++n) {
      int i = t + n * 256;
      float4 zv = zb4[i];
      float4 pv = pb4[i];
      float4 ev = eb4[i & 63];
      float4 c;
      c.x = pv.x + ev.x; c.y = pv.y + ev.y;
      c.z = pv.z + ev.z; c.w = pv.w + ev.w;
      s += 0.5f * dot4(zv, zv) - dot4(zv, c);
      // zf[frag=(p>>4)*8+ks][lane li][elems e0..e0+3];
      // row = 16*(p>>4)+(li&15) = p, col = ks*32+(li>>4)*8+j = 4*d4+j.  OK.
      int p = i >> 6, d4 = i & 63;
      int ks = d4 >> 3, sub = (d4 & 7) >> 1, e0 = (d4 & 1) * 4;
      int li = (p & 15) + sub * 16;
      ushort4 o;
      o.x = f2bf(zv.x); o.y = f2bf(zv.y); o.z = f2bf(zv.z); o.w = f2bf(zv.w);
      *(ushort4*)(SL + (size_t)(((p >> 4) * 8 + ks) * 64 + li) * 8 + e0) = o;
    }
  }
  __syncthreads();

  // ---- Phase 1: phi_mem (all 4 ct chunks; mem_v5 inner body).
#pragma unroll 1
  for (int ctl = 0; ctl < 4; ++ctl) {
    const ushort* Bb = mtf + ((size_t)(ctl * 16 + w * 4) * 8) * 512 +
                       (size_t)l * 8;
    short8 fb[2][4];
#pragma unroll
    for (int c = 0; c < 4; ++c) fb[0][c] = *(const short8*)(Bb + (c * 8 + 0) * 512);
#pragma unroll
    for (int c = 0; c < 4; ++c) fb[1][c] = *(const short8*)(Bb + (c * 8 + 1) * 512);

    f32x4 acc[4][4];
#pragma unroll
    for (int r = 0; r < 4; ++r)
#pragma unroll
      for (int c = 0; c < 4; ++c) acc[r][c] = f32x4{0.f, 0.f, 0.f, 0.f};

#pragma unroll
    for (int kc = 0; kc < 8; ++kc) {
      const int cur = kc & 1;
      short8 a4[4];
#pragma unroll
      for (int r = 0; r < 4; ++r)
        a4[r] = *(const short8*)(SL + (size_t)((r * 8 + kc) * 64 + l) * 8);
#pragma unroll
      for (int r = 0; r < 4; ++r)
#pragma unroll
        for (int c = 0; c < 4; ++c)
          acc[r][c] = __builtin_amdgcn_mfma_f32_16x16x32_bf16(a4[r], fb[cur][c],
                                                              acc[r][c], 0, 0, 0);
      if (kc < 6) {
#pragma unroll
        for (int c = 0; c < 4; ++c)
          fb[cur][c] = *(const short8*)(Bb + (c * 8 + kc + 2) * 512);
      }
    }
#pragma unroll
    for (int r = 0; r < 4; ++r)
#pragma unroll
      for (int c = 0; c < 4; ++c)
#pragma unroll
        for (int e = 0; e < 4; ++e) {
          float rr = fmaxf(acc[r][c][e], 0.f);
          s -= rr * rr;  // -= phi_mem contribution
        }
  }

  // ---- Phase 2: phi_att (both halves; attn_v6 proj + phase C).
  float part = 0.f;
  char* dstg = (char*)(SL + 16384);
#pragma unroll 1
  for (int half = 0; half < 2; ++half) {
    const ushort* Bb = wcf + ((size_t)((half * 16 + w * 4) * 8)) * 512 +
                       (size_t)l * 8;
    short8 fb[2][4];
#pragma unroll
    for (int c = 0; c < 4; ++c) fb[0][c] = *(const short8*)(Bb + (c * 8 + 0) * 512);
#pragma unroll
    for (int c = 0; c < 4; ++c) fb[1][c] = *(const short8*)(Bb + (c * 8 + 1) * 512);

    f32x4 acc[4][4];
#pragma unroll
    for (int r = 0; r < 4; ++r)
#pragma unroll
      for (int c = 0; c < 4; ++c) acc[r][c] = f32x4{0.f, 0.f, 0.f, 0.f};

#pragma unroll
    for (int kc = 0; kc < 8; ++kc) {
      const int cur = kc & 1;
      short8 a4[4];
#pragma unroll
      for (int r = 0; r < 4; ++r)
        a4[r] = *(const short8*)(SL + (size_t)((r * 8 + kc) * 64 + l) * 8);
#pragma unroll
      for (int r = 0; r < 4; ++r)
#pragma unroll
        for (int c = 0; c < 4; ++c)
          acc[r][c] = __builtin_amdgcn_mfma_f32_16x16x32_bf16(a4[r], fb[cur][c],
                                                              acc[r][c], 0, 0, 0);
      if (kc < 6) {
#pragma unroll
        for (int c = 0; c < 4; ++c)
          fb[cur][c] = *(const short8*)(Bb + (c * 8 + kc + 2) * 512);
      }
    }

    // D (row = 16rt+4q+reg, col = (4w+c)*16+m) -> bf16 -> dstg, XOR-swizzled.
#pragma unroll
    for (int rt = 0; rt < 4; ++rt)
#pragma unroll
      for (int c = 0; c < 4; ++c)
#pragma unroll
        for (int reg = 0; reg < 4; ++reg) {
          int row = 16 * rt + 4 * q + reg;
          int col = (4 * w + c) * 16 + m;
          int ba = ((row * 256 + col) * 2) ^ ((row & 7) << 4);
          *(ushort*)(dstg + ba) = f2bf(acc[rt][c][reg]);
        }
    __syncthreads();

    // Phase C: per head hh, Q rows 16w+m, K tiles nt; cols hh*64 (+32 for K).
#pragma unroll
    for (int hh = 0; hh < 4; ++hh) {
      int rowq = 16 * w + m;
      short8 qa = *(const short8*)(
          dstg + (((rowq * 256 + hh * 64 + q * 8) * 2) ^ ((rowq & 7) << 4)));
      f32x4 a2[4];
#pragma unroll
      for (int nt = 0; nt < 4; ++nt) {
        int rowk = 16 * nt + m;
        short8 kb = *(const short8*)(
            dstg + (((rowk * 256 + hh * 64 + 32 + q * 8) * 2) ^ ((rowk & 7) << 4)));
        a2[nt] = __builtin_amdgcn_mfma_f32_16x16x32_bf16(
            qa, kb, f32x4{0.f, 0.f, 0.f, 0.f}, 0, 0, 0);
      }
#pragma unroll
      for (int reg = 0; reg < 4; ++reg) {
        float e = __expf(GAMMA * a2[0][reg]) + __expf(GAMMA * a2[1][reg]) +
                  __expf(GAMMA * a2[2][reg]) + __expf(GAMMA * a2[3][reg]);
        e += __shfl_xor(e, 1, 64);
        e += __shfl_xor(e, 2, 64);
        e += __shfl_xor(e, 4, 64);
        e += __shfl_xor(e, 8, 64);
        part += (m == 0) ? __logf(e) : 0.f;  // one log per row 16w+4q+reg
      }
    }
    __syncthreads();  // dstg reads done before next half's writes
  }
  s -= part * (1.0f / GAMMA);

  float r = block_sum_256(s, (float*)SL);  // zf dead; reuse as tmp
  if (t == 0) out[b] = r;
}

// ---------------------------------------------------------------------------
// Kernel: quad_x - phi_vis - phi_enc (enc_v4 body; z A-frags from fp32 z).
// ---------------------------------------------------------------------------
__global__ __launch_bounds__(256) void k_enc_v5(
    const float* __restrict__ x, const float* __restrict__ vb,
    const float* __restrict__ z, const ushort* __restrict__ ewt,
    float* __restrict__ out) {
  __shared__ ushort xs[12288];      // 24 KB: x[b] bf16, NCHW layout
  __shared__ ushort ebuf[2][6144];  // 2 x 12 KB: ewt ks-chunk double buffer
  __shared__ float tmp[4];
  const int b = blockIdx.x, t = threadIdx.x, l = t & 63, w = t >> 6;
  const int q = l >> 4, m = l & 15;

  // z A-frags from fp32 (L3-warm after k_mega); RNE cvt == old zb16 values.
  const float* Zr = z + (size_t)b * 16384 + (size_t)(16 * w + m) * 256 + q * 8;
  short8 a[8];
#pragma unroll
  for (int ks = 0; ks < 8; ++ks) {
    float4 u = *(const float4*)(Zr + ks * 32);
    float4 v = *(const float4*)(Zr + ks * 32 + 4);
    ushort o[8];
    o[0] = f2bf(u.x); o[1] = f2bf(u.y); o[2] = f2bf(u.z); o[3] = f2bf(u.w);
    o[4] = f2bf(v.x); o[5] = f2bf(v.y); o[6] = f2bf(v.z); o[7] = f2bf(v.w);
    a[ks] = *(short8*)o;
  }

  // chunk-0 staging loads (in flight during x staging)
  short8 st[3];
#pragma unroll
  for (int i = 0; i < 3; ++i)
    st[i] = *(const short8*)(ewt + (size_t)(t + i * 256) * 8);

  // Stage x -> bf16 LDS; accumulate quad_x - phi_vis.
  const float4* xb = (const float4*)(x + (size_t)b * 12288);
  const float4* vb4 = (const float4*)vb;
  ushort4* xs4 = (ushort4*)xs;
  float s = 0.f;
  for (int i = t; i < 3072; i += 256) {
    float4 xv = xb[i];
    float4 bv = vb4[i];
    s += 0.5f * dot4(xv, xv) - dot4(bv, xv);
    ushort4 o;
    o.x = f2bf(xv.x); o.y = f2bf(xv.y); o.z = f2bf(xv.z); o.w = f2bf(xv.w);
    xs4[i] = o;
  }
#pragma unroll
  for (int i = 0; i < 3; ++i)
    *(short8*)(ebuf[0] + (size_t)(t + i * 256) * 8) = st[i];
  __syncthreads();

  f32x4 acc[12];
#pragma unroll
  for (int ct = 0; ct < 12; ++ct) acc[ct] = f32x4{0.f, 0.f, 0.f, 0.f};

#pragma unroll
  for (int ks = 0; ks < 8; ++ks) {
    const int cur = ks & 1;
    if (ks < 7) {
#pragma unroll
      for (int i = 0; i < 3; ++i)
        st[i] = *(const short8*)(ewt + (size_t)(ks + 1) * 6144 +
                                 (size_t)(t + i * 256) * 8);
    }
#pragma unroll
    for (int ct = 0; ct < 12; ++ct) {
      short8 bv = *(const short8*)(ebuf[cur] + (size_t)(ct * 64 + l) * 8);
      acc[ct] = __builtin_amdgcn_mfma_f32_16x16x32_bf16(a[ks], bv, acc[ct], 0, 0, 0);
    }
    if (ks < 7) {
#pragma unroll
      for (int i = 0; i < 3; ++i)
        *(short8*)(ebuf[cur ^ 1] + (size_t)(t + i * 256) * 8) = st[i];
    }
    __syncthreads();
  }

  // Epilogue: D element (row p=16w+4q+reg, col k=16ct+m) * x[p,k] from LDS.
#pragma unroll
  for (int ct = 0; ct < 12; ++ct) {
#pragma unroll
    for (int reg = 0; reg < 4; ++reg) {
      const int p = 16 * w + 4 * q + reg, gi = p >> 3, gj = p & 7;
      const int k = ct * 16 + m, c = k >> 6, r2 = k & 63;
      const int ii = r2 >> 3, jj = r2 & 7;
      s -= acc[ct][reg] * bf2f(xs[c * 4096 + (gi * 8 + ii) * 64 + gj * 8 + jj]);
    }
  }
  float r = block_sum_256(s, tmp);
  if (t == 0) atomicAdd(out + b, r);  // += quad_x - phi_vis - phi_enc
}

// ---------------------------------------------------------------------------
// Fallback kernels (no-workspace tier).
// ---------------------------------------------------------------------------
__global__ __launch_bounds__(256) void k_xz(const float* __restrict__ x,
                                            const float* __restrict__ z,
                                            const float* __restrict__ vb,
                                            const float* __restrict__ eb,
                                            const float* __restrict__ pb,
                                            float* __restrict__ out) {
  __shared__ float tmp[4];
  int b = blockIdx.x, t = threadIdx.x;
  const float4* xb = (const float4*)(x + (size_t)b * 12288);
  const float4* vb4 = (const float4*)vb;
  float s = 0.f;
  for (int i = t; i < 3072; i += 256) {
    float4 xv = xb[i];
    float4 bv = vb4[i];
    s += 0.5f * dot4(xv, xv) - dot4(bv, xv);
  }
  const float4* zb = (const float4*)(z + (size_t)b * 16384);
  const float4* pb4 = (const float4*)pb;
  const float4* eb4 = (const float4*)eb;
  for (int i = t; i < 4096; i += 256) {
    float4 zv = zb[i];
    float4 pv = pb4[i];
    float4 ev = eb4[i & 63];
    float4 c;
    c.x = pv.x + ev.x; c.y = pv.y + ev.y; c.z = pv.z + ev.z; c.w = pv.w + ev.w;
    s += 0.5f * dot4(zv, zv) - dot4(zv, c);
  }
  float r = block_sum_256(s, tmp);
  if (t == 0) out[b] = r;
}

__global__ __launch_bounds__(256) void k_enc(const float* __restrict__ x,
                                             const float* __restrict__ z,
                                             const float* __restrict__ ew,
                                             float* __restrict__ out) {
  __shared__ float xs[12288];
  __shared__ float tmp[4];
  int b = blockIdx.x, t = threadIdx.x;
  const float4* xb4 = (const float4*)(x + (size_t)b * 12288);
  for (int i = t; i < 3072; i += 256) ((float4*)xs)[i] = xb4[i];
  __syncthreads();

  float acc[64];
#pragma unroll
  for (int p = 0; p < 64; ++p) acc[p] = 0.f;

  for (int k4 = 0; k4 < 48; ++k4) {
    float4 wv = *(const float4*)(ew + (size_t)t * 192 + k4 * 4);
    int c = k4 >> 4;
    int ii = (k4 >> 1) & 7;
    int jh = (k4 & 1) * 4;
    const float* base = xs + c * 4096 + ii * 64 + jh;
#pragma unroll
    for (int p = 0; p < 64; ++p) {
      float4 pv = *(const float4*)(base + (p >> 3) * 512 + (p & 7) * 8);
      acc[p] = fmaf(wv.x, pv.x,
               fmaf(wv.y, pv.y, fmaf(wv.z, pv.z, fmaf(wv.w, pv.w, acc[p]))));
    }
  }
  const float* zb = z + (size_t)b * 16384;
  float s = 0.f;
#pragma unroll
  for (int p = 0; p < 64; ++p) s += acc[p] * zb[p * 256 + t];
  float r = block_sum_256(s, tmp);
  if (t == 0) atomicAdd(out + b, -r);
}

__global__ __launch_bounds__(256) void k_mem(const float* __restrict__ z,
                                             const float* __restrict__ mw,
                                             float* __restrict__ out) {
  __shared__ float zs[16 * 256];
  __shared__ float tmp[4];
  int b = blockIdx.x >> 2, pt = blockIdx.x & 3, t = threadIdx.x;
  const float4* zb4 = (const float4*)(z + (size_t)b * 16384 + pt * 4096);
  for (int i = t; i < 1024; i += 256) ((float4*)zs)[i] = zb4[i];
  __syncthreads();

  const float4* m4 = (const float4*)mw;
  float4 acc[16];
#pragma unroll
  for (int pp = 0; pp < 16; ++pp) acc[pp] = make_float4(0.f, 0.f, 0.f, 0.f);

#pragma unroll 2
  for (int k4 = 0; k4 < 64; ++k4) {
    float4 w0 = m4[(4 * k4 + 0) * 256 + t];
    float4 w1 = m4[(4 * k4 + 1) * 256 + t];
    float4 w2 = m4[(4 * k4 + 2) * 256 + t];
    float4 w3 = m4[(4 * k4 + 3) * 256 + t];
#pragma unroll
    for (int pp = 0; pp < 16; ++pp) {
      float4 zv = *(const float4*)&zs[pp * 256 + k4 * 4];
      fma4(acc[pp], zv.x, w0);
      fma4(acc[pp], zv.y, w1);
      fma4(acc[pp], zv.z, w2);
      fma4(acc[pp], zv.w, w3);
    }
  }
  float total = 0.f;
#pragma unroll
  for (int pp = 0; pp < 16; ++pp) {
    float r;
    r = fmaxf(acc[pp].x, 0.f); total = fmaf(r, r, total);
    r = fmaxf(acc[pp].y, 0.f); total = fmaf(r, r, total);
    r = fmaxf(acc[pp].z, 0.f); total = fmaf(r, r, total);
    r = fmaxf(acc[pp].w, 0.f); total = fmaf(r, r, total);
  }
  float r = block_sum_256(total, tmp);
  if (t == 0) atomicAdd(out + b, -r);
}

__global__ __launch_bounds__(256) void k_attn(const float* __restrict__ z,
                                              const float* __restrict__ wq,
                                              const float* __restrict__ wk,
                                              float* __restrict__ out) {
  __shared__ float lds[8192];
  __shared__ float red[4];
  const int b = blockIdx.x >> 1, half = blockIdx.x & 1;
  const int t = threadIdx.x;
  const int lane = t & 63;
  const int w = __builtin_amdgcn_readfirstlane(t >> 6);
  const float4* zb4 = (const float4*)(z + (size_t)b * 16384);

  float qa[4][8], ka[4][8];
#pragma unroll
  for (int hh = 0; hh < 4; ++hh)
#pragma unroll
    for (int j = 0; j < 8; ++j) { qa[hh][j] = 0.f; ka[hh][j] = 0.f; }

  float4* lds4 = (float4*)lds;
  for (int dc = 0; dc < 2; ++dc) {
    __syncthreads();
    for (int i = t; i < 2048; i += 256) {
      int p = i >> 5, ld4 = i & 31;
      lds4[ld4 * 64 + (p ^ (ld4 & 7))] = zb4[p * 64 + dc * 32 + ld4];
    }
    __syncthreads();
#pragma unroll
    for (int hh = 0; hh < 4; ++hh) {
      int h = half * 4 + hh;
      const float* Wqb = wq + (size_t)h * 8192 + (size_t)(w * 8) * 256 + dc * 128;
      const float* Wkb = wk + (size_t)h * 8192 + (size_t)(w * 8) * 256 + dc * 128;
      for (int ld4 = 0; ld4 < 32; ++ld4) {
        float4 wv[8], kv[8];
#pragma unroll
        for (int j = 0; j < 8; ++j) {
          wv[j] = *(const float4*)(Wqb + j * 256 + ld4 * 4);
          kv[j] = *(const float4*)(Wkb + j * 256 + ld4 * 4);
        }
        float4 zv = lds4[ld4 * 64 + (lane ^ (ld4 & 7))];
#pragma unroll
        for (int j = 0; j < 8; ++j) {
          qa[hh][j] = fmaf(wv[j].x, zv.x, fmaf(wv[j].y, zv.y,
                      fmaf(wv[j].z, zv.z, fmaf(wv[j].w, zv.w, qa[hh][j]))));
          ka[hh][j] = fmaf(kv[j].x, zv.x, fmaf(kv[j].y, zv.y,
                      fmaf(kv[j].z, zv.z, fmaf(kv[j].w, zv.w, ka[hh][j]))));
        }
      }
    }
  }

  float* Qs = lds;
  float* Ks = lds + 2048;
  float lse = 0.f;
#pragma unroll
  for (int hh = 0; hh < 4; ++hh) {
    __syncthreads();
#pragma unroll
    for (int j = 0; j < 8; ++j) {
      Qs[(w * 8 + j) * 64 + lane] = qa[hh][j];
      Ks[(w * 8 + j) * 64 + lane] = ka[hh][j];
    }
    __syncthreads();
    float av[16];
#pragma unroll
    for (int mm = 0; mm < 16; ++mm) av[mm] = 0.f;
    for (int rr = 0; rr < 32; ++rr) {
      float kv = Ks[rr * 64 + lane];
      const float* qrow = &Qs[rr * 64 + w * 16];
      float4 q0 = *(const float4*)(qrow + 0);
      float4 q1 = *(const float4*)(qrow + 4);
      float4 q2 = *(const float4*)(qrow + 8);
      float4 q3 = *(const float4*)(qrow + 12);
      av[0]  = fmaf(q0.x, kv, av[0]);  av[1]  = fmaf(q0.y, kv, av[1]);
      av[2]  = fmaf(q0.z, kv, av[2]);  av[3]  = fmaf(q0.w, kv, av[3]);
      av[4]  = fmaf(q1.x, kv, av[4]);  av[5]  = fmaf(q1.y, kv, av[5]);
      av[6]  = fmaf(q1.z, kv, av[6]);  av[7]  = fmaf(q1.w, kv, av[7]);
      av[8]  = fmaf(q2.x, kv, av[8]);  av[9]  = fmaf(q2.y, kv, av[9]);
      av[10] = fmaf(q2.z, kv, av[10]); av[11] = fmaf(q2.w, kv, av[11]);
      av[12] = fmaf(q3.x, kv, av[12]); av[13] = fmaf(q3.y, kv, av[13]);
      av[14] = fmaf(q3.z, kv, av[14]); av[15] = fmaf(q3.w, kv, av[15]);
    }
#pragma unroll
    for (int mm = 0; mm < 16; ++mm) {
      float e = __expf(GAMMA * av[mm]);
#pragma unroll
      for (int off = 32; off; off >>= 1) e += __shfl_xor(e, off, 64);
      lse += __logf(e);
    }
  }
  if (lane == 0) red[w] = lse;
  __syncthreads();
  if (t == 0)
    atomicAdd(out + b, -(red[0] + red[1] + red[2] + red[3]) * (1.0f / GAMMA));
}

// ---------------------------------------------------------------------------
extern "C" void kernel_launch(void* const* d_in, const int* in_sizes, int n_in,
                              void* d_out, int out_size, void* d_ws,
                              size_t ws_size, hipStream_t stream) {
  (void)in_sizes; (void)n_in; (void)out_size;
  const float* x  = (const float*)d_in[0];
  const float* z  = (const float*)d_in[1];
  const float* ew = (const float*)d_in[2];
  const float* eb = (const float*)d_in[3];
  const float* vb = (const float*)d_in[4];
  const float* pb = (const float*)d_in[5];
  const float* mw = (const float*)d_in[6];
  const float* wq = (const float*)d_in[7];
  const float* wk = (const float*)d_in[8];
  float* out = (float*)d_out;

  const size_t MT_B = (size_t)1024 * 256 * 2;   // 512 KB mtf
  const size_t WC_B = (size_t)512 * 256 * 2;    // 256 KB wcf
  const size_t EW_B = (size_t)96 * 64 * 8 * 2;  // 96 KB ewt
  const size_t FULL = MT_B + WC_B + EW_B;       // ~0.86 MB

  ushort* mtf = (ushort*)d_ws;
  ushort* wcf = (ushort*)((char*)d_ws + MT_B);
  ushort* ewt = (ushort*)((char*)d_ws + MT_B + WC_B);

  if (ws_size >= FULL) {
    k_cvt_weights_v4<<<216, 256, 0, stream>>>(wq, wk, ew, mw, wcf, ewt, mtf);
    k_mega  <<<1024, 256, 0, stream>>>(z, eb, pb, mtf, wcf, out);
    k_enc_v5<<<1024, 256, 0, stream>>>(x, vb, z, ewt, out);
  } else {
    k_xz  <<<1024, 256, 0, stream>>>(x, z, vb, eb, pb, out);
    k_enc <<<1024, 256, 0, stream>>>(x, z, ew, out);
    k_mem <<<4096, 256, 0, stream>>>(z, mw, out);
    k_attn<<<2048, 256, 0, stream>>>(z, wq, wk, out);
  }
}